// Round 1
// 802.666 us; speedup vs baseline: 1.1083x; 1.1083x over previous
//
#include <hip/hip_runtime.h>
#include <math.h>

#define DIM 2048
#define SEQ 2048
#define NH 16
#define NKV 8
#define HD 128
#define HIDDEN 5632
#define QKV_N 4096   // (16 + 2*8) * 128
#define FF_N 11264   // 2*HIDDEN

typedef __attribute__((ext_vector_type(8))) short s16x8;   // 8 bf16 (4 VGPRs) MFMA A/B frag
typedef __attribute__((ext_vector_type(4))) float f32x4;   // MFMA C/D frag

#define GPTR(p) ((const __attribute__((address_space(1))) void*)(p))
#define LPTR(p) ((__attribute__((address_space(3))) void*)(p))

// Compiler memory fence + HW barrier. Raw s_barrier (NOT __syncthreads) so the
// compiler does not emit a vmcnt(0) drain -- counted vmcnt is the whole point.
#define CFENCE() __asm__ __volatile__("" ::: "memory")
#define BAR() do { CFENCE(); __builtin_amdgcn_s_barrier(); CFENCE(); } while (0)

__device__ __forceinline__ unsigned short f2bf(float f) {
    union { float f; unsigned u; } v; v.f = f;
    unsigned r = v.u + 0x7fff + ((v.u >> 16) & 1);   // RNE
    return (unsigned short)(r >> 16);
}
__device__ __forceinline__ float bf2f(unsigned short s) {
    union { unsigned u; float f; } v; v.u = ((unsigned)s) << 16;
    return v.f;
}

// ---------------- fp32 -> bf16 convert (weights) ----------------
__global__ __launch_bounds__(256) void k_cvt(const float* __restrict__ src,
                                             unsigned short* __restrict__ dst, int n4) {
    int i = blockIdx.x * 256 + threadIdx.x;
    if (i < n4) {
        float4 v = ((const float4*)src)[i];
        ushort4 o;
        o.x = f2bf(v.x); o.y = f2bf(v.y); o.z = f2bf(v.z); o.w = f2bf(v.w);
        ((ushort4*)dst)[i] = o;
    }
}

// ---------------- RMSNorm (fp32 in) -> bf16 out ----------------
__global__ __launch_bounds__(256) void k_rmsnorm(const float* __restrict__ x,
                                                 const float* __restrict__ w,
                                                 unsigned short* __restrict__ out) {
    int row = blockIdx.x;
    int tid = threadIdx.x, wv = tid >> 6, lane = tid & 63;
    const float* xr = x + (size_t)row * DIM;
    float4 a = ((const float4*)xr)[tid * 2];
    float4 b = ((const float4*)xr)[tid * 2 + 1];
    float ss = a.x*a.x + a.y*a.y + a.z*a.z + a.w*a.w
             + b.x*b.x + b.y*b.y + b.z*b.z + b.w*b.w;
    for (int off = 32; off >= 1; off >>= 1) ss += __shfl_xor(ss, off);
    __shared__ float red[4];
    if (lane == 0) red[wv] = ss;
    __syncthreads();
    float tot = red[0] + red[1] + red[2] + red[3];
    float rs = rsqrtf(tot * (1.0f / DIM) + 1e-5f);
    float4 wa = ((const float4*)w)[tid * 2];
    float4 wb = ((const float4*)w)[tid * 2 + 1];
    ushort4 o0, o1;
    o0.x = f2bf(a.x * rs * wa.x); o0.y = f2bf(a.y * rs * wa.y);
    o0.z = f2bf(a.z * rs * wa.z); o0.w = f2bf(a.w * rs * wa.w);
    o1.x = f2bf(b.x * rs * wb.x); o1.y = f2bf(b.y * rs * wb.y);
    o1.z = f2bf(b.z * rs * wb.z); o1.w = f2bf(b.w * rs * wb.w);
    ushort4* orow = (ushort4*)(out + (size_t)row * DIM);
    orow[tid * 2] = o0; orow[tid * 2 + 1] = o1;
}

// ---------------- bf16 GEMM: C[M,N] = A[M,K] @ B[N,K]^T (+fused epilogue) ----
// 256x256 tile, BK=64, 8 waves (2Mx4N), double-buffered LDS (128 KiB, 1 blk/CU),
// 4-phase counted-vmcnt schedule (T3+T4) + setprio around MFMA clusters (T5).
//
// Per K-tile T (buf b=T&1), 4 phases, each = {ds_read; stage-issue; BAR;
// lgkmcnt(0); 16 MFMA; BAR}:
//   p0: read A-k0(8 b128)+B-k0(4); stage (T+1)-Ak1 -> buf b^1; MFMA nt01*ks0
//   p1: read B-k1(4);              stage (T+2)-Ak0 -> buf b;   MFMA nt23*ks0
//   p2: read A-k1(8);              stage (T+2)-Bk0 -> buf b;   MFMA nt01*ks1
//   p3: (no reads);                stage (T+2)-Bk1 -> buf b;   MFMA nt23*ks1
//       then s_waitcnt vmcnt(6) (allow newest 3 half-tiles in flight), BAR.
// Safety invariant: a region staged at phase p is only ds_read at phases < p
// of the same group (reads are lgkm-drained before each phase's MFMA, i.e.
// before the next phase's stage issue), so in-flight LDS writes can never
// clobber a pending read. vmcnt(6) before group entry guarantees the whole
// tile landed (its newest half is 4th-newest in the issue order).
// Tail groups (prefetch guards skipped) degrade to vmcnt(0). Requires NT>=2.
//
// LDS layout per matrix per buf: [kg 0..7][row 0..255][8 bf16] -- fragment-
// contiguous, ds_read_b128 measured conflict-free (rocprof: 0), and staging
// "pre-swizzles" the global source so global_load_lds dests stay linear.
// flags: 0 = fp32 out (at Cf + z*M*N for split-K), 1 = +add residual, 2 = bf16.
template<int ID>
__global__ __launch_bounds__(512, 2) void k_gemm256(
    const unsigned short* __restrict__ A, const unsigned short* __restrict__ B,
    int M, int N, int K, int Kslice,
    float* __restrict__ Cf, unsigned short* __restrict__ Cb,
    const float* __restrict__ add, int flags) {
    __shared__ __align__(16) unsigned short As[2][16384];   // 2 x 32 KB
    __shared__ __align__(16) unsigned short Bs[2][16384];
    int tid = threadIdx.x;
    int wv = tid >> 6, lane = tid & 63, quad = lane >> 4, l15 = lane & 15;
    int wr = wv >> 2, wc = wv & 3;          // wave grid 2 (M) x 4 (N)
    int rowBase = blockIdx.y * 256;
    int colBase = blockIdx.x * 256;
    int kb = blockIdx.z * Kslice;
    int NT = Kslice >> 6;

    f32x4 acc[8][4] = {};

    // Stage one 16 KB half-tile (kh: 0 = k 0..31, 1 = k 32..63) of K-tile t.
    // 2 x global_load_lds_dwordx4 per thread; LDS dest is wave-uniform base +
    // lane*16 (HW requirement); per-lane global addr carries the layout.
    auto stageA = [&](int t, int kh, int b) {
#pragma unroll
        for (int j = 0; j < 2; j++) {
            int u = j * 8 + wv;          // 0..15
            int kg = u >> 2;             // 0..3
            int m0 = (u & 3) * 64;
            const unsigned short* g = A + (size_t)(rowBase + m0 + lane) * K
                                        + (kb + t * 64 + kh * 32 + kg * 8);
            __builtin_amdgcn_global_load_lds(GPTR(g),
                LPTR(&As[b][((kh * 4 + kg) * 256 + m0) * 8]), 16, 0, 0);
        }
    };
    auto stageB = [&](int t, int kh, int b) {
#pragma unroll
        for (int j = 0; j < 2; j++) {
            int u = j * 8 + wv;
            int kg = u >> 2;
            int m0 = (u & 3) * 64;
            const unsigned short* g = B + (size_t)(colBase + m0 + lane) * K
                                        + (kb + t * 64 + kh * 32 + kg * 8);
            __builtin_amdgcn_global_load_lds(GPTR(g),
                LPTR(&Bs[b][((kh * 4 + kg) * 256 + m0) * 8]), 16, 0, 0);
        }
    };

    // Prologue: tile0 {Ak0,Bk0,Bk1,Ak1} -> buf0; tile1 {Ak0,Bk0,Bk1} -> buf1.
    // (tile1-Ak1 is staged by group0 p0.) 14 loads; vmcnt(6) leaves tile1's
    // newest 3 halves in flight, guarantees tile0 landed.
    stageA(0, 0, 0); stageB(0, 0, 0); stageB(0, 1, 0); stageA(0, 1, 0);
    if (NT > 1) {
        stageA(1, 0, 1); stageB(1, 0, 1); stageB(1, 1, 1);
        asm volatile("s_waitcnt vmcnt(6)" ::: "memory");
    } else {
        asm volatile("s_waitcnt vmcnt(0)" ::: "memory");
    }
    BAR();

    for (int T = 0; T < NT; T++) {
        const int b = T & 1;
        s16x8 a0[8], a1[8], b0[4], b1[4];
        // ---- phase 0 ----
#pragma unroll
        for (int mt = 0; mt < 8; mt++)
            a0[mt] = *(const s16x8*)&As[b][(quad * 256 + wr * 128 + mt * 16 + l15) * 8];
#pragma unroll
        for (int nt = 0; nt < 4; nt++)
            b0[nt] = *(const s16x8*)&Bs[b][(quad * 256 + wc * 64 + nt * 16 + l15) * 8];
        if (T + 1 < NT) stageA(T + 1, 1, b ^ 1);
        BAR();
        asm volatile("s_waitcnt lgkmcnt(0)" ::: "memory");
        __builtin_amdgcn_s_setprio(1);
#pragma unroll
        for (int mt = 0; mt < 8; mt++) {
            acc[mt][0] = __builtin_amdgcn_mfma_f32_16x16x32_bf16(a0[mt], b0[0], acc[mt][0], 0, 0, 0);
            acc[mt][1] = __builtin_amdgcn_mfma_f32_16x16x32_bf16(a0[mt], b0[1], acc[mt][1], 0, 0, 0);
        }
        __builtin_amdgcn_s_setprio(0);
        BAR();
        // ---- phase 1 ----
#pragma unroll
        for (int nt = 0; nt < 4; nt++)
            b1[nt] = *(const s16x8*)&Bs[b][((4 + quad) * 256 + wc * 64 + nt * 16 + l15) * 8];
        if (T + 2 < NT) stageA(T + 2, 0, b);
        BAR();
        asm volatile("s_waitcnt lgkmcnt(0)" ::: "memory");
        __builtin_amdgcn_s_setprio(1);
#pragma unroll
        for (int mt = 0; mt < 8; mt++) {
            acc[mt][2] = __builtin_amdgcn_mfma_f32_16x16x32_bf16(a0[mt], b0[2], acc[mt][2], 0, 0, 0);
            acc[mt][3] = __builtin_amdgcn_mfma_f32_16x16x32_bf16(a0[mt], b0[3], acc[mt][3], 0, 0, 0);
        }
        __builtin_amdgcn_s_setprio(0);
        BAR();
        // ---- phase 2 ----
#pragma unroll
        for (int mt = 0; mt < 8; mt++)
            a1[mt] = *(const s16x8*)&As[b][((4 + quad) * 256 + wr * 128 + mt * 16 + l15) * 8];
        if (T + 2 < NT) stageB(T + 2, 0, b);
        BAR();
        asm volatile("s_waitcnt lgkmcnt(0)" ::: "memory");
        __builtin_amdgcn_s_setprio(1);
#pragma unroll
        for (int mt = 0; mt < 8; mt++) {
            acc[mt][0] = __builtin_amdgcn_mfma_f32_16x16x32_bf16(a1[mt], b1[0], acc[mt][0], 0, 0, 0);
            acc[mt][1] = __builtin_amdgcn_mfma_f32_16x16x32_bf16(a1[mt], b1[1], acc[mt][1], 0, 0, 0);
        }
        __builtin_amdgcn_s_setprio(0);
        BAR();
        // ---- phase 3 ----
        if (T + 2 < NT) stageB(T + 2, 1, b);
        BAR();
        __builtin_amdgcn_s_setprio(1);
#pragma unroll
        for (int mt = 0; mt < 8; mt++) {
            acc[mt][2] = __builtin_amdgcn_mfma_f32_16x16x32_bf16(a1[mt], b1[2], acc[mt][2], 0, 0, 0);
            acc[mt][3] = __builtin_amdgcn_mfma_f32_16x16x32_bf16(a1[mt], b1[3], acc[mt][3], 0, 0, 0);
        }
        __builtin_amdgcn_s_setprio(0);
        if (T + 2 < NT) asm volatile("s_waitcnt vmcnt(6)" ::: "memory");
        else            asm volatile("s_waitcnt vmcnt(0)" ::: "memory");
        BAR();
    }

    float* Cfz = Cf ? Cf + (size_t)blockIdx.z * M * N : nullptr;
#pragma unroll
    for (int mt = 0; mt < 8; mt++)
#pragma unroll
        for (int nt = 0; nt < 4; nt++)
#pragma unroll
            for (int r = 0; r < 4; r++) {
                int row = rowBase + wr * 128 + mt * 16 + quad * 4 + r;
                int col = colBase + wc * 64 + nt * 16 + l15;
                size_t idx = (size_t)row * N + col;
                float v = acc[mt][nt][r];
                if (flags == 1) v += add[idx];
                if (flags == 2) Cb[idx] = f2bf(v);
                else            Cfz[idx] = v;
            }
}

// ---------------- 5-way add (split-K x4 reduce + residual) ----------------
__global__ __launch_bounds__(256) void k_red5(const float* __restrict__ p,
                                              size_t pstride,
                                              const float* __restrict__ res,
                                              float* __restrict__ o, int n4) {
    int i = blockIdx.x * 256 + threadIdx.x;
    if (i < n4) {
        float4 r = ((const float4*)res)[i];
#pragma unroll
        for (int z = 0; z < 4; z++) {
            float4 v = ((const float4*)(p + z * pstride))[i];
            r.x += v.x; r.y += v.y; r.z += v.z; r.w += v.w;
        }
        ((float4*)o)[i] = r;
    }
}

// ---------------- per-head LayerNorm + RoPE for Q and K ----------------
// One wave per (s, head). Q: writes [16][SEQ][128] bf16, pre-scaled by log2e/sqrt(128).
// K: writes fragment-contiguous global layout [kvh][kt(32)][dgrp(16)][key(64)][8].
__global__ __launch_bounds__(256) void k_qknorm_rope(
    const float* __restrict__ qkv,
    const float* __restrict__ qw, const float* __restrict__ qb,
    const float* __restrict__ kw, const float* __restrict__ kb,
    const float* __restrict__ fcos, const float* __restrict__ fsin,
    unsigned short* __restrict__ qout, unsigned short* __restrict__ kfrag) {
    int wv = threadIdx.x >> 6, lane = threadIdx.x & 63;
    int hl = blockIdx.y;              // 0..15 q-head, 16..23 k-head
    int s = blockIdx.x * 4 + wv;
    bool isq = hl < 16;
    float2 xv = *(const float2*)&qkv[(size_t)s * QKV_N + hl * HD + 2 * lane];
    float sum = xv.x + xv.y, ssq = xv.x * xv.x + xv.y * xv.y;
    for (int off = 32; off >= 1; off >>= 1) {
        sum += __shfl_xor(sum, off);
        ssq += __shfl_xor(ssq, off);
    }
    float mu = sum * (1.0f / HD);
    float var = ssq * (1.0f / HD) - mu * mu;
    float rs = rsqrtf(var + 1e-5f);
    const float* w_ = isq ? qw : kw;
    const float* b_ = isq ? qb : kb;
    float n0 = (xv.x - mu) * rs * w_[2 * lane]     + b_[2 * lane];
    float n1 = (xv.y - mu) * rs * w_[2 * lane + 1] + b_[2 * lane + 1];
    float c = fcos[s * 64 + lane], sn = fsin[s * 64 + lane];
    float o0 = n0 * c - n1 * sn;
    float o1 = n0 * sn + n1 * c;
    if (isq) {
        const float sc = 0.12751744f;  // (1/sqrt(128)) * log2(e): softmax scale + exp2 fold
        o0 *= sc; o1 *= sc;
        unsigned val = (unsigned)f2bf(o0) | ((unsigned)f2bf(o1) << 16);
        *(unsigned*)&qout[((size_t)hl * SEQ + s) * HD + 2 * lane] = val;
    } else {
        int kvh = hl - 16;
        int kt = s >> 6, key = s & 63;
        int dg = lane >> 2, j = (2 * lane) & 7;
        unsigned val = (unsigned)f2bf(o0) | ((unsigned)f2bf(o1) << 16);
        size_t idx = (((size_t)(kvh * 32 + kt) * 16 + dg) * 64 + key) * 8 + j;
        *(unsigned*)&kfrag[idx] = val;
    }
}

// ---------------- V: fp32 -> bf16, into fragment-contiguous layout -----------
// out layout: [kvh][kt(32)][kgrp(8)][d(128)][8 keys]
__global__ __launch_bounds__(256) void k_vprep(const float* __restrict__ qkv,
                                               unsigned short* __restrict__ vfrag) {
    __shared__ unsigned short lv[64][132];
    int kvh = blockIdx.y, kt = blockIdx.x, tid = threadIdx.x;
#pragma unroll
    for (int it = 0; it < 8; it++) {
        int li = it * 256 + tid;          // float4 index among 64*32
        int row = li >> 5;
        int c4 = (li & 31) * 4;
        float4 v = *(const float4*)&qkv[(size_t)(kt * 64 + row) * QKV_N + 3072 + kvh * HD + c4];
        lv[row][c4] = f2bf(v.x); lv[row][c4 + 1] = f2bf(v.y);
        lv[row][c4 + 2] = f2bf(v.z); lv[row][c4 + 3] = f2bf(v.w);
    }
    __syncthreads();
    size_t base = (size_t)(kvh * 32 + kt) * 8192;
#pragma unroll
    for (int it = 0; it < 16; it++) {
        int o2 = it * 256 + tid;          // uint index among 4096
        int e = o2 * 2;
        int r = e & 7, d = (e >> 3) & 127, kg = e >> 10;
        unsigned val = (unsigned)lv[kg * 8 + r][d] | ((unsigned)lv[kg * 8 + r + 1][d] << 16);
        *(unsigned*)&vfrag[base + e] = val;
    }
}

// ---------------- Flash attention, causal, GQA (2 q-heads per kv-head) ------
__global__ __launch_bounds__(256) void k_flash(
    const unsigned short* __restrict__ q,      // [16][SEQ][128], pre-scaled
    const unsigned short* __restrict__ kfrag,  // [8][32][16][64][8]
    const unsigned short* __restrict__ vfrag,  // [8][32][8][128][8]
    unsigned short* __restrict__ o) {          // [SEQ][2048]
    __shared__ __align__(16) unsigned short Ks[2][8192];
    __shared__ __align__(16) unsigned short Vs[2][8192];
    __shared__ __align__(16) unsigned short Ps[4][16 * 72];   // pad stride 72 (144B, 16B-aligned)
    int h = blockIdx.x & 15;
    int qt = 31 - (blockIdx.x >> 4);     // heavy (large qt) blocks launch first
    int kvh = h >> 1;
    int tid = threadIdx.x, wv = tid >> 6, lane = tid & 63, quad = lane >> 4, l15 = lane & 15;
    int qbase = qt * 64;

    s16x8 qf[4];
    {
        const unsigned short* qp = q + ((size_t)h * SEQ + qbase + wv * 16 + l15) * HD + quad * 8;
#pragma unroll
        for (int ks = 0; ks < 4; ks++) qf[ks] = *(const s16x8*)(qp + ks * 32);
    }
    f32x4 oacc[8] = {};
    float mst[4], lst[4];
#pragma unroll
    for (int r = 0; r < 4; r++) { mst[r] = -3e38f; lst[r] = 0.f; }

    auto issueKV = [&](int kt, int b) {
        size_t kb = (size_t)(kvh * 32 + kt) * 8192;
#pragma unroll
        for (int i = 0; i < 4; i++) {
            int s0 = i * 256 + wv * 64;
            __builtin_amdgcn_global_load_lds(GPTR(kfrag + kb + (size_t)(s0 + lane) * 8), LPTR(&Ks[b][s0 * 8]), 16, 0, 0);
            __builtin_amdgcn_global_load_lds(GPTR(vfrag + kb + (size_t)(s0 + lane) * 8), LPTR(&Vs[b][s0 * 8]), 16, 0, 0);
        }
    };

    issueKV(0, 0);
    for (int kt = 0; kt <= qt; kt++) {
        int b = kt & 1;
        __syncthreads();
        if (kt < qt) issueKV(kt + 1, b ^ 1);

        f32x4 sacc[4];
#pragma unroll
        for (int nt = 0; nt < 4; nt++) {
            f32x4 a = {};
#pragma unroll
            for (int ks = 0; ks < 4; ks++) {
                s16x8 kf = *(const s16x8*)&Ks[b][((ks * 4 + quad) * 64 + nt * 16 + l15) * 8];
                a = __builtin_amdgcn_mfma_f32_16x16x32_bf16(qf[ks], kf, a, 0, 0, 0);
            }
            sacc[nt] = a;
        }
        if (kt == qt) {   // diagonal tile: mask key > query
#pragma unroll
            for (int nt = 0; nt < 4; nt++) {
                int colg = kt * 64 + nt * 16 + l15;
#pragma unroll
                for (int r = 0; r < 4; r++) {
                    int rowg = qbase + wv * 16 + quad * 4 + r;
                    if (colg > rowg) sacc[nt][r] = -3e38f;
                }
            }
        }
        unsigned short* Pw = Ps[wv];
#pragma unroll
        for (int r = 0; r < 4; r++) {
            float mx = fmaxf(fmaxf(sacc[0][r], sacc[1][r]), fmaxf(sacc[2][r], sacc[3][r]));
#pragma unroll
            for (int off = 1; off < 16; off <<= 1) mx = fmaxf(mx, __shfl_xor(mx, off));
            float mnew = fmaxf(mst[r], mx);
            float alpha = exp2f(mst[r] - mnew);
            float psum = 0.f;
#pragma unroll
            for (int nt = 0; nt < 4; nt++) {
                float p = exp2f(sacc[nt][r] - mnew);
                psum += p;
                Pw[(quad * 4 + r) * 72 + nt * 16 + l15] = f2bf(p);
            }
#pragma unroll
            for (int off = 1; off < 16; off <<= 1) psum += __shfl_xor(psum, off);
            lst[r] = lst[r] * alpha + psum;
            mst[r] = mnew;
#pragma unroll
            for (int vt = 0; vt < 8; vt++) oacc[vt][r] *= alpha;
        }
        // PV: P through LDS into A-operand layout (m120-verified transform)
#pragma unroll
        for (int ks = 0; ks < 2; ks++) {
            s16x8 pf = *(const s16x8*)&Pw[l15 * 72 + ks * 32 + quad * 8];
#pragma unroll
            for (int vt = 0; vt < 8; vt++) {
                s16x8 vf = *(const s16x8*)&Vs[b][((ks * 4 + quad) * 128 + vt * 16 + l15) * 8];
                oacc[vt] = __builtin_amdgcn_mfma_f32_16x16x32_bf16(pf, vf, oacc[vt], 0, 0, 0);
            }
        }
    }
#pragma unroll
    for (int r = 0; r < 4; r++) {
        float inv = 1.0f / lst[r];
        int row = qbase + wv * 16 + quad * 4 + r;
#pragma unroll
        for (int vt = 0; vt < 8; vt++)
            o[(size_t)row * DIM + h * HD + vt * 16 + l15] = f2bf(oacc[vt][r] * inv);
    }
}

// ---------------- SwiGLU: y = silu(x1) * x3 ----------------
__global__ __launch_bounds__(256) void k_silu(const unsigned short* __restrict__ x13,
                                              unsigned short* __restrict__ y) {
    int gid = blockIdx.x * 256 + threadIdx.x;     // [0, 2048*1408)
    int s = gid / 1408;
    int j4 = (gid - s * 1408) * 4;
    const unsigned short* p1 = x13 + (size_t)s * FF_N + j4;
    const unsigned short* p3 = p1 + HIDDEN;
    ushort4 a = *(const ushort4*)p1;
    ushort4 b = *(const ushort4*)p3;
    ushort4 o;
    {
        float x1 = bf2f(a.x), x3 = bf2f(b.x);
        o.x = f2bf(x1 / (1.f + __expf(-x1)) * x3);
    }
    {
        float x1 = bf2f(a.y), x3 = bf2f(b.y);
        o.y = f2bf(x1 / (1.f + __expf(-x1)) * x3);
    }
    {
        float x1 = bf2f(a.z), x3 = bf2f(b.z);
        o.z = f2bf(x1 / (1.f + __expf(-x1)) * x3);
    }
    {
        float x1 = bf2f(a.w), x3 = bf2f(b.w);
        o.w = f2bf(x1 / (1.f + __expf(-x1)) * x3);
    }
    *(ushort4*)&y[(size_t)s * HIDDEN + j4] = o;
}

extern "C" void kernel_launch(void* const* d_in, const int* in_sizes, int n_in,
                              void* d_out, int out_size, void* d_ws, size_t ws_size,
                              hipStream_t stream) {
    const float* x    = (const float*)d_in[0];
    const float* fcos = (const float*)d_in[1];
    const float* fsin = (const float*)d_in[2];
    // d_in[3] = mask: causal, implemented directly
    const float* wqkv = (const float*)d_in[4];
    const float* wo   = (const float*)d_in[5];
    const float* qn_w = (const float*)d_in[6];
    const float* qn_b = (const float*)d_in[7];
    const float* kn_w = (const float*)d_in[8];
    const float* kn_b = (const float*)d_in[9];
    const float* anw  = (const float*)d_in[10];
    const float* fnw  = (const float*)d_in[11];
    const float* w13  = (const float*)d_in[12];
    const float* w2   = (const float*)d_in[13];
    float* out = (float*)d_out;
    char* ws = (char*)d_ws;

    size_t off = 0;
    auto alloc = [&](size_t bytes) { size_t o = off; off += (bytes + 255) & ~(size_t)255; return o; };
    unsigned short* wqkv_b = (unsigned short*)(ws + alloc((size_t)QKV_N * DIM * 2));
    unsigned short* wo_b   = (unsigned short*)(ws + alloc((size_t)DIM * DIM * 2));
    unsigned short* w13_b  = (unsigned short*)(ws + alloc((size_t)FF_N * DIM * 2));
    unsigned short* w2_b   = (unsigned short*)(ws + alloc((size_t)DIM * HIDDEN * 2));
    unsigned short* xn     = (unsigned short*)(ws + alloc((size_t)SEQ * DIM * 2));
    float*          qkv    = (float*)         (ws + alloc((size_t)SEQ * QKV_N * 4));
    unsigned short* qb_    = (unsigned short*)(ws + alloc((size_t)NH * SEQ * HD * 2));
    unsigned short* kfr    = (unsigned short*)(ws + alloc((size_t)NKV * SEQ * HD * 2));
    unsigned short* vfr    = (unsigned short*)(ws + alloc((size_t)NKV * SEQ * HD * 2));
    unsigned short* ob     = (unsigned short*)(ws + alloc((size_t)SEQ * DIM * 2));
    float*          hbuf   = (float*)         (ws + alloc((size_t)SEQ * DIM * 4));
    unsigned short* gb     = (unsigned short*)(ws + alloc((size_t)SEQ * DIM * 2));
    unsigned short* x13b   = (unsigned short*)(ws + alloc((size_t)SEQ * FF_N * 2));
    unsigned short* yb     = (unsigned short*)(ws + alloc((size_t)SEQ * HIDDEN * 2));
    float*          pp     = (float*)         (ws + alloc((size_t)4 * SEQ * DIM * 4));
    const size_t pstride = (size_t)SEQ * DIM;

    // weight conversions (per-call; ws is re-poisoned each launch)
    k_cvt<<<8192, 256, 0, stream>>>(wqkv, wqkv_b, QKV_N * DIM / 4);
    k_cvt<<<4096, 256, 0, stream>>>(wo, wo_b, DIM * DIM / 4);
    k_cvt<<<22528, 256, 0, stream>>>(w13, w13_b, FF_N * DIM / 4);
    k_cvt<<<11264, 256, 0, stream>>>(w2, w2_b, DIM * HIDDEN / 4);

    // h = rmsnorm(x, attn_norm_w) -> bf16
    k_rmsnorm<<<SEQ, 256, 0, stream>>>(x, anw, xn);
    // qkv = h @ wqkv^T (fp32 out); 16x8 = 128 blocks, NT=32
    k_gemm256<0><<<dim3(QKV_N / 256, SEQ / 256), 512, 0, stream>>>(
        xn, wqkv_b, SEQ, QKV_N, DIM, DIM, qkv, nullptr, nullptr, 0);
    // per-head LN + RoPE, write q (scaled) and k (frag layout)
    k_qknorm_rope<<<dim3(SEQ / 4, NH + NKV), 256, 0, stream>>>(
        qkv, qn_w, qn_b, kn_w, kn_b, fcos, fsin, qb_, kfr);
    // v -> bf16 frag layout
    k_vprep<<<dim3(SEQ / 64, NKV), 256, 0, stream>>>(qkv, vfr);
    // flash attention
    k_flash<<<NH * (SEQ / 64), 256, 0, stream>>>(qb_, kfr, vfr, ob);
    // attn proj, split-K x4 (8x8x4 = 256 blocks, NT=8); hbuf = x + sum(partials)
    k_gemm256<1><<<dim3(DIM / 256, SEQ / 256, 4), 512, 0, stream>>>(
        ob, wo_b, SEQ, DIM, DIM, DIM / 4, pp, nullptr, nullptr, 0);
    k_red5<<<SEQ * DIM / 1024, 256, 0, stream>>>(pp, pstride, x, hbuf, SEQ * DIM / 4);
    // g = rmsnorm(h, ffn_norm_w) -> bf16
    k_rmsnorm<<<SEQ, 256, 0, stream>>>(hbuf, fnw, gb);
    // x13 = g @ w13^T (bf16 out); 44x8 = 352 blocks, NT=32
    k_gemm256<2><<<dim3(FF_N / 256, SEQ / 256), 512, 0, stream>>>(
        gb, w13_b, SEQ, FF_N, DIM, DIM, nullptr, x13b, nullptr, 2);
    // y = silu(x1) * x3
    k_silu<<<SEQ * (HIDDEN / 4) / 256, 256, 0, stream>>>(x13b, yb);
    // FFN down, split-K x4 (NT=22); out = hbuf + sum(partials)
    k_gemm256<3><<<dim3(DIM / 256, SEQ / 256, 4), 512, 0, stream>>>(
        yb, w2_b, SEQ, DIM, HIDDEN, HIDDEN / 4, pp, nullptr, nullptr, 0);
    k_red5<<<SEQ * DIM / 1024, 256, 0, stream>>>(pp, pstride, hbuf, out, SEQ * DIM / 4);
}

// Round 2
// 747.389 us; speedup vs baseline: 1.1903x; 1.0740x over previous
//
#include <hip/hip_runtime.h>
#include <math.h>

#define DIM 2048
#define SEQ 2048
#define NH 16
#define NKV 8
#define HD 128
#define HIDDEN 5632
#define QKV_N 4096   // (16 + 2*8) * 128
#define FF_N 11264   // 2*HIDDEN

typedef __attribute__((ext_vector_type(8))) short s16x8;   // 8 bf16 (4 VGPRs) MFMA A/B frag
typedef __attribute__((ext_vector_type(4))) float f32x4;   // MFMA C/D frag

#define GPTR(p) ((const __attribute__((address_space(1))) void*)(p))
#define LPTR(p) ((__attribute__((address_space(3))) void*)(p))

// Compiler memory fence + HW barrier. Raw s_barrier (NOT __syncthreads) so the
// compiler does not emit a vmcnt(0) drain -- counted vmcnt is the whole point.
#define CFENCE() __asm__ __volatile__("" ::: "memory")
#define BAR() do { CFENCE(); __builtin_amdgcn_s_barrier(); CFENCE(); } while (0)

__device__ __forceinline__ unsigned short f2bf(float f) {
    union { float f; unsigned u; } v; v.f = f;
    unsigned r = v.u + 0x7fff + ((v.u >> 16) & 1);   // RNE
    return (unsigned short)(r >> 16);
}
__device__ __forceinline__ float bf2f(unsigned short s) {
    union { unsigned u; float f; } v; v.u = ((unsigned)s) << 16;
    return v.f;
}

// ---------------- fp32 -> bf16 convert (weights) ----------------
__global__ __launch_bounds__(256) void k_cvt(const float* __restrict__ src,
                                             unsigned short* __restrict__ dst, int n4) {
    int i = blockIdx.x * 256 + threadIdx.x;
    if (i < n4) {
        float4 v = ((const float4*)src)[i];
        ushort4 o;
        o.x = f2bf(v.x); o.y = f2bf(v.y); o.z = f2bf(v.z); o.w = f2bf(v.w);
        ((ushort4*)dst)[i] = o;
    }
}

// ---------------- RMSNorm (fp32 in) -> bf16 out ----------------
__global__ __launch_bounds__(256) void k_rmsnorm(const float* __restrict__ x,
                                                 const float* __restrict__ w,
                                                 unsigned short* __restrict__ out) {
    int row = blockIdx.x;
    int tid = threadIdx.x, wv = tid >> 6, lane = tid & 63;
    const float* xr = x + (size_t)row * DIM;
    float4 a = ((const float4*)xr)[tid * 2];
    float4 b = ((const float4*)xr)[tid * 2 + 1];
    float ss = a.x*a.x + a.y*a.y + a.z*a.z + a.w*a.w
             + b.x*b.x + b.y*b.y + b.z*b.z + b.w*b.w;
    for (int off = 32; off >= 1; off >>= 1) ss += __shfl_xor(ss, off);
    __shared__ float red[4];
    if (lane == 0) red[wv] = ss;
    __syncthreads();
    float tot = red[0] + red[1] + red[2] + red[3];
    float rs = rsqrtf(tot * (1.0f / DIM) + 1e-5f);
    float4 wa = ((const float4*)w)[tid * 2];
    float4 wb = ((const float4*)w)[tid * 2 + 1];
    ushort4 o0, o1;
    o0.x = f2bf(a.x * rs * wa.x); o0.y = f2bf(a.y * rs * wa.y);
    o0.z = f2bf(a.z * rs * wa.z); o0.w = f2bf(a.w * rs * wa.w);
    o1.x = f2bf(b.x * rs * wb.x); o1.y = f2bf(b.y * rs * wb.y);
    o1.z = f2bf(b.z * rs * wb.z); o1.w = f2bf(b.w * rs * wb.w);
    ushort4* orow = (ushort4*)(out + (size_t)row * DIM);
    orow[tid * 2] = o0; orow[tid * 2 + 1] = o1;
}

// ---------------- bf16 GEMM: C[M,N] = A[M,K] @ B[N,K]^T (+fused epilogue) ----
// 256x256 tile, BK=64, 8 waves (2Mx4N), double-buffered LDS (128 KiB, 1 blk/CU),
// 4-phase counted-vmcnt schedule + setprio around MFMA clusters.
//
// R2 fix (the R0/R1 bottleneck): staging is now COALESCED. LDS holds row-major
// [256 rows][64 k] bf16 per matrix per buf; each global_load_lds instruction
// covers 8 rows x 128 B contiguous (8 cache lines, vs 64 scattered 16 B rows
// before -- 8x less TA pressure, which was ~4000 cyc/K-tile of VMEM issue).
// The 16-way ds_read bank conflict this layout would cause is killed by an
// XOR involution (T2 / rule #21): stage source chunk = (l&7) ^ (row&7) (LDS
// dest stays linear, required by global_load_lds), ds_read chunk =
// (ks*4+quad) ^ (row&7). Net bank distribution: 8 lanes per bank-quad =
// the conflict-free floor for ds_read_b128.
//
// Per K-tile T (buf b=T&1), 4 phases, each = {ds_read; stage; BAR; lgkmcnt(0);
// 16 MFMA (setprio-wrapped); BAR}:
//   p0: read A-ks0(8) + B-ks0(4);  no stage;                MFMA a0*b0[0,1]
//   p1: read B-ks1(4);             no stage;                MFMA a0*b0[2,3]
//   p2: read A-ks1(8);             stage B(T+2) both halves; MFMA a1*b1[0,1]
//   p3: no reads;                  stage A(T+2) both halves; MFMA a1*b1[2,3]
//       then vmcnt(8) (8 loads of T+2 in flight; forces T+1 landed), BAR.
// Region safety: B rows of buf b are fully consumed by end of p1 (reads
// drained at p1's lgkmcnt before p1-end BAR) -> stageable at p2. A rows
// consumed by end of p2 -> stageable at p3. Tail degrades to vmcnt(0).
// flags: 0 = fp32 out (at Cf + z*M*N for split-K), 1 = +add residual, 2 = bf16.
template<int ID>
__global__ __launch_bounds__(512, 2) void k_gemm256(
    const unsigned short* __restrict__ A, const unsigned short* __restrict__ B,
    int M, int N, int K, int Kslice,
    float* __restrict__ Cf, unsigned short* __restrict__ Cb,
    const float* __restrict__ add, int flags) {
    __shared__ __align__(16) unsigned short As[2][16384];   // [buf][row 256][k 64]
    __shared__ __align__(16) unsigned short Bs[2][16384];
    int tid = threadIdx.x;
    int wv = tid >> 6, lane = tid & 63, quad = lane >> 4, l15 = lane & 15;
    int wr = wv >> 2, wc = wv & 3;          // wave grid 2 (M) x 4 (N)
    int rowBase = blockIdx.y * 256;
    int colBase = blockIdx.x * 256;
    int kb = blockIdx.z * Kslice;
    int NT = Kslice >> 6;

    f32x4 acc[8][4] = {};

    int srow = lane >> 3;      // row within the 8-row group of one stage instr
    int schunk = lane & 7;     // linear LDS 16B-chunk within the row

    // Stage rows [128h, 128h+128) of K-tile t of one matrix into buf b.
    // 2 wave-instrs x 8 rows x 128 B contiguous each; source chunk XOR-swizzled
    // so that swizzled ds_reads find A[row][chunk] at LDS[row][chunk^(row&7)].
    auto stage = [&](const unsigned short* Mat, int matBase,
                     unsigned short (*Ls)[16384], int t, int h, int b) {
#pragma unroll
        for (int j = 0; j < 2; j++) {
            int r0 = h * 128 + (j * 8 + wv) * 8;
            int row = r0 + srow;
            int kchunk = schunk ^ (row & 7);
            const unsigned short* g = Mat + (size_t)(matBase + row) * K
                                      + (kb + t * 64 + kchunk * 8);
            __builtin_amdgcn_global_load_lds(GPTR(g), LPTR(&Ls[b][r0 * 64]), 16, 0, 0);
        }
    };
    auto LDA = [&](int b_, int mt, int ks) -> s16x8 {
        int row = wr * 128 + mt * 16 + l15;
        return *(const s16x8*)&As[b_][row * 64 + ((((ks * 4 + quad)) ^ (row & 7)) << 3)];
    };
    auto LDB = [&](int b_, int nt, int ks) -> s16x8 {
        int row = wc * 64 + nt * 16 + l15;
        return *(const s16x8*)&Bs[b_][row * 64 + ((((ks * 4 + quad)) ^ (row & 7)) << 3)];
    };

    // Prologue: tile0 -> buf0 (8 loads/thread), tile1 -> buf1 (8 loads/thread).
    // vmcnt(8) forces tile0 landed, leaves tile1's 8 in flight.
    stage(B, colBase, Bs, 0, 0, 0); stage(B, colBase, Bs, 0, 1, 0);
    stage(A, rowBase, As, 0, 0, 0); stage(A, rowBase, As, 0, 1, 0);
    if (NT > 1) {
        stage(B, colBase, Bs, 1, 0, 1); stage(B, colBase, Bs, 1, 1, 1);
        stage(A, rowBase, As, 1, 0, 1); stage(A, rowBase, As, 1, 1, 1);
        asm volatile("s_waitcnt vmcnt(8)" ::: "memory");
    } else {
        asm volatile("s_waitcnt vmcnt(0)" ::: "memory");
    }
    BAR();

    for (int T = 0; T < NT; T++) {
        const int b = T & 1;
        s16x8 a0[8], a1[8], b0[4], b1[4];
        // ---- phase 0 ----
#pragma unroll
        for (int mt = 0; mt < 8; mt++) a0[mt] = LDA(b, mt, 0);
#pragma unroll
        for (int nt = 0; nt < 4; nt++) b0[nt] = LDB(b, nt, 0);
        BAR();
        asm volatile("s_waitcnt lgkmcnt(0)" ::: "memory");
        __builtin_amdgcn_s_setprio(1);
#pragma unroll
        for (int mt = 0; mt < 8; mt++) {
            acc[mt][0] = __builtin_amdgcn_mfma_f32_16x16x32_bf16(a0[mt], b0[0], acc[mt][0], 0, 0, 0);
            acc[mt][1] = __builtin_amdgcn_mfma_f32_16x16x32_bf16(a0[mt], b0[1], acc[mt][1], 0, 0, 0);
        }
        __builtin_amdgcn_s_setprio(0);
        BAR();
        // ---- phase 1 ----
#pragma unroll
        for (int nt = 0; nt < 4; nt++) b1[nt] = LDB(b, nt, 1);
        BAR();
        asm volatile("s_waitcnt lgkmcnt(0)" ::: "memory");
        __builtin_amdgcn_s_setprio(1);
#pragma unroll
        for (int mt = 0; mt < 8; mt++) {
            acc[mt][2] = __builtin_amdgcn_mfma_f32_16x16x32_bf16(a0[mt], b0[2], acc[mt][2], 0, 0, 0);
            acc[mt][3] = __builtin_amdgcn_mfma_f32_16x16x32_bf16(a0[mt], b0[3], acc[mt][3], 0, 0, 0);
        }
        __builtin_amdgcn_s_setprio(0);
        BAR();
        // ---- phase 2 ----
#pragma unroll
        for (int mt = 0; mt < 8; mt++) a1[mt] = LDA(b, mt, 1);
        if (T + 2 < NT) { stage(B, colBase, Bs, T + 2, 0, b); stage(B, colBase, Bs, T + 2, 1, b); }
        BAR();
        asm volatile("s_waitcnt lgkmcnt(0)" ::: "memory");
        __builtin_amdgcn_s_setprio(1);
#pragma unroll
        for (int mt = 0; mt < 8; mt++) {
            acc[mt][0] = __builtin_amdgcn_mfma_f32_16x16x32_bf16(a1[mt], b1[0], acc[mt][0], 0, 0, 0);
            acc[mt][1] = __builtin_amdgcn_mfma_f32_16x16x32_bf16(a1[mt], b1[1], acc[mt][1], 0, 0, 0);
        }
        __builtin_amdgcn_s_setprio(0);
        BAR();
        // ---- phase 3 ----
        if (T + 2 < NT) { stage(A, rowBase, As, T + 2, 0, b); stage(A, rowBase, As, T + 2, 1, b); }
        BAR();
        __builtin_amdgcn_s_setprio(1);
#pragma unroll
        for (int mt = 0; mt < 8; mt++) {
            acc[mt][2] = __builtin_amdgcn_mfma_f32_16x16x32_bf16(a1[mt], b1[2], acc[mt][2], 0, 0, 0);
            acc[mt][3] = __builtin_amdgcn_mfma_f32_16x16x32_bf16(a1[mt], b1[3], acc[mt][3], 0, 0, 0);
        }
        __builtin_amdgcn_s_setprio(0);
        if (T + 2 < NT) asm volatile("s_waitcnt vmcnt(8)" ::: "memory");
        else            asm volatile("s_waitcnt vmcnt(0)" ::: "memory");
        BAR();
    }

    float* Cfz = Cf ? Cf + (size_t)blockIdx.z * M * N : nullptr;
#pragma unroll
    for (int mt = 0; mt < 8; mt++)
#pragma unroll
        for (int nt = 0; nt < 4; nt++)
#pragma unroll
            for (int r = 0; r < 4; r++) {
                int row = rowBase + wr * 128 + mt * 16 + quad * 4 + r;
                int col = colBase + wc * 64 + nt * 16 + l15;
                size_t idx = (size_t)row * N + col;
                float v = acc[mt][nt][r];
                if (flags == 1) v += add[idx];
                if (flags == 2) Cb[idx] = f2bf(v);
                else            Cfz[idx] = v;
            }
}

// ---------------- 5-way add (split-K x4 reduce + residual) ----------------
__global__ __launch_bounds__(256) void k_red5(const float* __restrict__ p,
                                              size_t pstride,
                                              const float* __restrict__ res,
                                              float* __restrict__ o, int n4) {
    int i = blockIdx.x * 256 + threadIdx.x;
    if (i < n4) {
        float4 r = ((const float4*)res)[i];
#pragma unroll
        for (int z = 0; z < 4; z++) {
            float4 v = ((const float4*)(p + z * pstride))[i];
            r.x += v.x; r.y += v.y; r.z += v.z; r.w += v.w;
        }
        ((float4*)o)[i] = r;
    }
}

// ---------------- per-head LayerNorm + RoPE for Q and K ----------------
// One wave per (s, head). Q: writes [16][SEQ][128] bf16, pre-scaled by log2e/sqrt(128).
// K: writes fragment-contiguous global layout [kvh][kt(32)][dgrp(16)][key(64)][8].
__global__ __launch_bounds__(256) void k_qknorm_rope(
    const float* __restrict__ qkv,
    const float* __restrict__ qw, const float* __restrict__ qb,
    const float* __restrict__ kw, const float* __restrict__ kb,
    const float* __restrict__ fcos, const float* __restrict__ fsin,
    unsigned short* __restrict__ qout, unsigned short* __restrict__ kfrag) {
    int wv = threadIdx.x >> 6, lane = threadIdx.x & 63;
    int hl = blockIdx.y;              // 0..15 q-head, 16..23 k-head
    int s = blockIdx.x * 4 + wv;
    bool isq = hl < 16;
    float2 xv = *(const float2*)&qkv[(size_t)s * QKV_N + hl * HD + 2 * lane];
    float sum = xv.x + xv.y, ssq = xv.x * xv.x + xv.y * xv.y;
    for (int off = 32; off >= 1; off >>= 1) {
        sum += __shfl_xor(sum, off);
        ssq += __shfl_xor(ssq, off);
    }
    float mu = sum * (1.0f / HD);
    float var = ssq * (1.0f / HD) - mu * mu;
    float rs = rsqrtf(var + 1e-5f);
    const float* w_ = isq ? qw : kw;
    const float* b_ = isq ? qb : kb;
    float n0 = (xv.x - mu) * rs * w_[2 * lane]     + b_[2 * lane];
    float n1 = (xv.y - mu) * rs * w_[2 * lane + 1] + b_[2 * lane + 1];
    float c = fcos[s * 64 + lane], sn = fsin[s * 64 + lane];
    float o0 = n0 * c - n1 * sn;
    float o1 = n0 * sn + n1 * c;
    if (isq) {
        const float sc = 0.12751744f;  // (1/sqrt(128)) * log2(e): softmax scale + exp2 fold
        o0 *= sc; o1 *= sc;
        unsigned val = (unsigned)f2bf(o0) | ((unsigned)f2bf(o1) << 16);
        *(unsigned*)&qout[((size_t)hl * SEQ + s) * HD + 2 * lane] = val;
    } else {
        int kvh = hl - 16;
        int kt = s >> 6, key = s & 63;
        int dg = lane >> 2, j = (2 * lane) & 7;
        unsigned val = (unsigned)f2bf(o0) | ((unsigned)f2bf(o1) << 16);
        size_t idx = (((size_t)(kvh * 32 + kt) * 16 + dg) * 64 + key) * 8 + j;
        *(unsigned*)&kfrag[idx] = val;
    }
}

// ---------------- V: fp32 -> bf16, into fragment-contiguous layout -----------
// out layout: [kvh][kt(32)][kgrp(8)][d(128)][8 keys]
__global__ __launch_bounds__(256) void k_vprep(const float* __restrict__ qkv,
                                               unsigned short* __restrict__ vfrag) {
    __shared__ unsigned short lv[64][132];
    int kvh = blockIdx.y, kt = blockIdx.x, tid = threadIdx.x;
#pragma unroll
    for (int it = 0; it < 8; it++) {
        int li = it * 256 + tid;          // float4 index among 64*32
        int row = li >> 5;
        int c4 = (li & 31) * 4;
        float4 v = *(const float4*)&qkv[(size_t)(kt * 64 + row) * QKV_N + 3072 + kvh * HD + c4];
        lv[row][c4] = f2bf(v.x); lv[row][c4 + 1] = f2bf(v.y);
        lv[row][c4 + 2] = f2bf(v.z); lv[row][c4 + 3] = f2bf(v.w);
    }
    __syncthreads();
    size_t base = (size_t)(kvh * 32 + kt) * 8192;
#pragma unroll
    for (int it = 0; it < 16; it++) {
        int o2 = it * 256 + tid;          // uint index among 4096
        int e = o2 * 2;
        int r = e & 7, d = (e >> 3) & 127, kg = e >> 10;
        unsigned val = (unsigned)lv[kg * 8 + r][d] | ((unsigned)lv[kg * 8 + r + 1][d] << 16);
        *(unsigned*)&vfrag[base + e] = val;
    }
}

// ---------------- Flash attention, causal, GQA (2 q-heads per kv-head) ------
__global__ __launch_bounds__(256) void k_flash(
    const unsigned short* __restrict__ q,      // [16][SEQ][128], pre-scaled
    const unsigned short* __restrict__ kfrag,  // [8][32][16][64][8]
    const unsigned short* __restrict__ vfrag,  // [8][32][8][128][8]
    unsigned short* __restrict__ o) {          // [SEQ][2048]
    __shared__ __align__(16) unsigned short Ks[2][8192];
    __shared__ __align__(16) unsigned short Vs[2][8192];
    __shared__ __align__(16) unsigned short Ps[4][16 * 72];   // pad stride 72 (144B, 16B-aligned)
    int h = blockIdx.x & 15;
    int qt = 31 - (blockIdx.x >> 4);     // heavy (large qt) blocks launch first
    int kvh = h >> 1;
    int tid = threadIdx.x, wv = tid >> 6, lane = tid & 63, quad = lane >> 4, l15 = lane & 15;
    int qbase = qt * 64;

    s16x8 qf[4];
    {
        const unsigned short* qp = q + ((size_t)h * SEQ + qbase + wv * 16 + l15) * HD + quad * 8;
#pragma unroll
        for (int ks = 0; ks < 4; ks++) qf[ks] = *(const s16x8*)(qp + ks * 32);
    }
    f32x4 oacc[8] = {};
    float mst[4], lst[4];
#pragma unroll
    for (int r = 0; r < 4; r++) { mst[r] = -3e38f; lst[r] = 0.f; }

    auto issueKV = [&](int kt, int b) {
        size_t kb = (size_t)(kvh * 32 + kt) * 8192;
#pragma unroll
        for (int i = 0; i < 4; i++) {
            int s0 = i * 256 + wv * 64;
            __builtin_amdgcn_global_load_lds(GPTR(kfrag + kb + (size_t)(s0 + lane) * 8), LPTR(&Ks[b][s0 * 8]), 16, 0, 0);
            __builtin_amdgcn_global_load_lds(GPTR(vfrag + kb + (size_t)(s0 + lane) * 8), LPTR(&Vs[b][s0 * 8]), 16, 0, 0);
        }
    };

    issueKV(0, 0);
    for (int kt = 0; kt <= qt; kt++) {
        int b = kt & 1;
        __syncthreads();
        if (kt < qt) issueKV(kt + 1, b ^ 1);

        f32x4 sacc[4];
#pragma unroll
        for (int nt = 0; nt < 4; nt++) {
            f32x4 a = {};
#pragma unroll
            for (int ks = 0; ks < 4; ks++) {
                s16x8 kf = *(const s16x8*)&Ks[b][((ks * 4 + quad) * 64 + nt * 16 + l15) * 8];
                a = __builtin_amdgcn_mfma_f32_16x16x32_bf16(qf[ks], kf, a, 0, 0, 0);
            }
            sacc[nt] = a;
        }
        if (kt == qt) {   // diagonal tile: mask key > query
#pragma unroll
            for (int nt = 0; nt < 4; nt++) {
                int colg = kt * 64 + nt * 16 + l15;
#pragma unroll
                for (int r = 0; r < 4; r++) {
                    int rowg = qbase + wv * 16 + quad * 4 + r;
                    if (colg > rowg) sacc[nt][r] = -3e38f;
                }
            }
        }
        unsigned short* Pw = Ps[wv];
#pragma unroll
        for (int r = 0; r < 4; r++) {
            float mx = fmaxf(fmaxf(sacc[0][r], sacc[1][r]), fmaxf(sacc[2][r], sacc[3][r]));
#pragma unroll
            for (int off = 1; off < 16; off <<= 1) mx = fmaxf(mx, __shfl_xor(mx, off));
            float mnew = fmaxf(mst[r], mx);
            float alpha = exp2f(mst[r] - mnew);
            float psum = 0.f;
#pragma unroll
            for (int nt = 0; nt < 4; nt++) {
                float p = exp2f(sacc[nt][r] - mnew);
                psum += p;
                Pw[(quad * 4 + r) * 72 + nt * 16 + l15] = f2bf(p);
            }
#pragma unroll
            for (int off = 1; off < 16; off <<= 1) psum += __shfl_xor(psum, off);
            lst[r] = lst[r] * alpha + psum;
            mst[r] = mnew;
#pragma unroll
            for (int vt = 0; vt < 8; vt++) oacc[vt][r] *= alpha;
        }
        // PV: P through LDS into A-operand layout (m120-verified transform)
#pragma unroll
        for (int ks = 0; ks < 2; ks++) {
            s16x8 pf = *(const s16x8*)&Pw[l15 * 72 + ks * 32 + quad * 8];
#pragma unroll
            for (int vt = 0; vt < 8; vt++) {
                s16x8 vf = *(const s16x8*)&Vs[b][((ks * 4 + quad) * 128 + vt * 16 + l15) * 8];
                oacc[vt] = __builtin_amdgcn_mfma_f32_16x16x32_bf16(pf, vf, oacc[vt], 0, 0, 0);
            }
        }
    }
#pragma unroll
    for (int r = 0; r < 4; r++) {
        float inv = 1.0f / lst[r];
        int row = qbase + wv * 16 + quad * 4 + r;
#pragma unroll
        for (int vt = 0; vt < 8; vt++)
            o[(size_t)row * DIM + h * HD + vt * 16 + l15] = f2bf(oacc[vt][r] * inv);
    }
}

// ---------------- SwiGLU: y = silu(x1) * x3 ----------------
__global__ __launch_bounds__(256) void k_silu(const unsigned short* __restrict__ x13,
                                              unsigned short* __restrict__ y) {
    int gid = blockIdx.x * 256 + threadIdx.x;     // [0, 2048*1408)
    int s = gid / 1408;
    int j4 = (gid - s * 1408) * 4;
    const unsigned short* p1 = x13 + (size_t)s * FF_N + j4;
    const unsigned short* p3 = p1 + HIDDEN;
    ushort4 a = *(const ushort4*)p1;
    ushort4 b = *(const ushort4*)p3;
    ushort4 o;
    {
        float x1 = bf2f(a.x), x3 = bf2f(b.x);
        o.x = f2bf(x1 / (1.f + __expf(-x1)) * x3);
    }
    {
        float x1 = bf2f(a.y), x3 = bf2f(b.y);
        o.y = f2bf(x1 / (1.f + __expf(-x1)) * x3);
    }
    {
        float x1 = bf2f(a.z), x3 = bf2f(b.z);
        o.z = f2bf(x1 / (1.f + __expf(-x1)) * x3);
    }
    {
        float x1 = bf2f(a.w), x3 = bf2f(b.w);
        o.w = f2bf(x1 / (1.f + __expf(-x1)) * x3);
    }
    *(ushort4*)&y[(size_t)s * HIDDEN + j4] = o;
}

extern "C" void kernel_launch(void* const* d_in, const int* in_sizes, int n_in,
                              void* d_out, int out_size, void* d_ws, size_t ws_size,
                              hipStream_t stream) {
    const float* x    = (const float*)d_in[0];
    const float* fcos = (const float*)d_in[1];
    const float* fsin = (const float*)d_in[2];
    // d_in[3] = mask: causal, implemented directly
    const float* wqkv = (const float*)d_in[4];
    const float* wo   = (const float*)d_in[5];
    const float* qn_w = (const float*)d_in[6];
    const float* qn_b = (const float*)d_in[7];
    const float* kn_w = (const float*)d_in[8];
    const float* kn_b = (const float*)d_in[9];
    const float* anw  = (const float*)d_in[10];
    const float* fnw  = (const float*)d_in[11];
    const float* w13  = (const float*)d_in[12];
    const float* w2   = (const float*)d_in[13];
    float* out = (float*)d_out;
    char* ws = (char*)d_ws;

    size_t off = 0;
    auto alloc = [&](size_t bytes) { size_t o = off; off += (bytes + 255) & ~(size_t)255; return o; };
    unsigned short* wqkv_b = (unsigned short*)(ws + alloc((size_t)QKV_N * DIM * 2));
    unsigned short* wo_b   = (unsigned short*)(ws + alloc((size_t)DIM * DIM * 2));
    unsigned short* w13_b  = (unsigned short*)(ws + alloc((size_t)FF_N * DIM * 2));
    unsigned short* w2_b   = (unsigned short*)(ws + alloc((size_t)DIM * HIDDEN * 2));
    unsigned short* xn     = (unsigned short*)(ws + alloc((size_t)SEQ * DIM * 2));
    float*          qkv    = (float*)         (ws + alloc((size_t)SEQ * QKV_N * 4));
    unsigned short* qb_    = (unsigned short*)(ws + alloc((size_t)NH * SEQ * HD * 2));
    unsigned short* kfr    = (unsigned short*)(ws + alloc((size_t)NKV * SEQ * HD * 2));
    unsigned short* vfr    = (unsigned short*)(ws + alloc((size_t)NKV * SEQ * HD * 2));
    unsigned short* ob     = (unsigned short*)(ws + alloc((size_t)SEQ * DIM * 2));
    float*          hbuf   = (float*)         (ws + alloc((size_t)SEQ * DIM * 4));
    unsigned short* gb     = (unsigned short*)(ws + alloc((size_t)SEQ * DIM * 2));
    unsigned short* x13b   = (unsigned short*)(ws + alloc((size_t)SEQ * FF_N * 2));
    unsigned short* yb     = (unsigned short*)(ws + alloc((size_t)SEQ * HIDDEN * 2));
    float*          pp     = (float*)         (ws + alloc((size_t)4 * SEQ * DIM * 4));
    const size_t pstride = (size_t)SEQ * DIM;

    // weight conversions (per-call; ws is re-poisoned each launch)
    k_cvt<<<8192, 256, 0, stream>>>(wqkv, wqkv_b, QKV_N * DIM / 4);
    k_cvt<<<4096, 256, 0, stream>>>(wo, wo_b, DIM * DIM / 4);
    k_cvt<<<22528, 256, 0, stream>>>(w13, w13_b, FF_N * DIM / 4);
    k_cvt<<<11264, 256, 0, stream>>>(w2, w2_b, DIM * HIDDEN / 4);

    // h = rmsnorm(x, attn_norm_w) -> bf16
    k_rmsnorm<<<SEQ, 256, 0, stream>>>(x, anw, xn);
    // qkv = h @ wqkv^T (fp32 out); 16x8 = 128 blocks, NT=32
    k_gemm256<0><<<dim3(QKV_N / 256, SEQ / 256), 512, 0, stream>>>(
        xn, wqkv_b, SEQ, QKV_N, DIM, DIM, qkv, nullptr, nullptr, 0);
    // per-head LN + RoPE, write q (scaled) and k (frag layout)
    k_qknorm_rope<<<dim3(SEQ / 4, NH + NKV), 256, 0, stream>>>(
        qkv, qn_w, qn_b, kn_w, kn_b, fcos, fsin, qb_, kfr);
    // v -> bf16 frag layout
    k_vprep<<<dim3(SEQ / 64, NKV), 256, 0, stream>>>(qkv, vfr);
    // flash attention
    k_flash<<<NH * (SEQ / 64), 256, 0, stream>>>(qb_, kfr, vfr, ob);
    // attn proj, split-K x4 (8x8x4 = 256 blocks, NT=8); hbuf = x + sum(partials)
    k_gemm256<1><<<dim3(DIM / 256, SEQ / 256, 4), 512, 0, stream>>>(
        ob, wo_b, SEQ, DIM, DIM, DIM / 4, pp, nullptr, nullptr, 0);
    k_red5<<<SEQ * DIM / 1024, 256, 0, stream>>>(pp, pstride, x, hbuf, SEQ * DIM / 4);
    // g = rmsnorm(h, ffn_norm_w) -> bf16
    k_rmsnorm<<<SEQ, 256, 0, stream>>>(hbuf, fnw, gb);
    // x13 = g @ w13^T (bf16 out); 44x8 = 352 blocks, NT=32
    k_gemm256<2><<<dim3(FF_N / 256, SEQ / 256), 512, 0, stream>>>(
        gb, w13_b, SEQ, FF_N, DIM, DIM, nullptr, x13b, nullptr, 2);
    // y = silu(x1) * x3
    k_silu<<<SEQ * (HIDDEN / 4) / 256, 256, 0, stream>>>(x13b, yb);
    // FFN down, split-K x4 (NT=22); out = hbuf + sum(partials)
    k_gemm256<3><<<dim3(DIM / 256, SEQ / 256, 4), 512, 0, stream>>>(
        yb, w2_b, SEQ, DIM, HIDDEN, HIDDEN / 4, pp, nullptr, nullptr, 0);
    k_red5<<<SEQ * DIM / 1024, 256, 0, stream>>>(pp, pstride, hbuf, out, SEQ * DIM / 4);
}

// Round 5
// 677.756 us; speedup vs baseline: 1.3126x; 1.1027x over previous
//
#include <hip/hip_runtime.h>
#include <math.h>

#define DIM 2048
#define SEQ 2048
#define NH 16
#define NKV 8
#define HD 128
#define HIDDEN 5632
#define QKV_N 4096   // (16 + 2*8) * 128
#define FF_N 11264   // 2*HIDDEN

typedef __attribute__((ext_vector_type(8))) short s16x8;   // 8 bf16 (4 VGPRs) MFMA A/B frag
typedef __attribute__((ext_vector_type(4))) float f32x4;   // MFMA C/D frag

#define GPTR(p) ((const __attribute__((address_space(1))) void*)(p))
#define LPTR(p) ((__attribute__((address_space(3))) void*)(p))

// Compiler memory fence + HW barrier. Raw s_barrier (NOT __syncthreads) so the
// compiler does not emit a vmcnt(0) drain -- counted vmcnt is the whole point.
#define CFENCE() __asm__ __volatile__("" ::: "memory")
#define BAR() do { CFENCE(); __builtin_amdgcn_s_barrier(); CFENCE(); } while (0)

__device__ __forceinline__ unsigned short f2bf(float f) {
    union { float f; unsigned u; } v; v.f = f;
    unsigned r = v.u + 0x7fff + ((v.u >> 16) & 1);   // RNE
    return (unsigned short)(r >> 16);
}
__device__ __forceinline__ float bf2f(unsigned short s) {
    union { unsigned u; float f; } v; v.u = ((unsigned)s) << 16;
    return v.f;
}

// ---------------- fp32 -> bf16 convert (weights) ----------------
__global__ __launch_bounds__(256) void k_cvt(const float* __restrict__ src,
                                             unsigned short* __restrict__ dst, int n4) {
    int i = blockIdx.x * 256 + threadIdx.x;
    if (i < n4) {
        float4 v = ((const float4*)src)[i];
        ushort4 o;
        o.x = f2bf(v.x); o.y = f2bf(v.y); o.z = f2bf(v.z); o.w = f2bf(v.w);
        ((ushort4*)dst)[i] = o;
    }
}

// ---------------- RMSNorm (fp32 in) -> bf16 out ----------------
__global__ __launch_bounds__(256) void k_rmsnorm(const float* __restrict__ x,
                                                 const float* __restrict__ w,
                                                 unsigned short* __restrict__ out) {
    int row = blockIdx.x;
    int tid = threadIdx.x, wv = tid >> 6, lane = tid & 63;
    const float* xr = x + (size_t)row * DIM;
    float4 a = ((const float4*)xr)[tid * 2];
    float4 b = ((const float4*)xr)[tid * 2 + 1];
    float ss = a.x*a.x + a.y*a.y + a.z*a.z + a.w*a.w
             + b.x*b.x + b.y*b.y + b.z*b.z + b.w*b.w;
    for (int off = 32; off >= 1; off >>= 1) ss += __shfl_xor(ss, off);
    __shared__ float red[4];
    if (lane == 0) red[wv] = ss;
    __syncthreads();
    float tot = red[0] + red[1] + red[2] + red[3];
    float rs = rsqrtf(tot * (1.0f / DIM) + 1e-5f);
    float4 wa = ((const float4*)w)[tid * 2];
    float4 wb = ((const float4*)w)[tid * 2 + 1];
    ushort4 o0, o1;
    o0.x = f2bf(a.x * rs * wa.x); o0.y = f2bf(a.y * rs * wa.y);
    o0.z = f2bf(a.z * rs * wa.z); o0.w = f2bf(a.w * rs * wa.w);
    o1.x = f2bf(b.x * rs * wb.x); o1.y = f2bf(b.y * rs * wb.y);
    o1.z = f2bf(b.z * rs * wb.z); o1.w = f2bf(b.w * rs * wb.w);
    ushort4* orow = (ushort4*)(out + (size_t)row * DIM);
    orow[tid * 2] = o0; orow[tid * 2 + 1] = o1;
}

// ---------------- bf16 GEMM: C[M,N] = A[M,K] @ B[N,K]^T (+fused epilogue) ----
// 256x256 tile, BK=64, 8 waves (2Mx4N), double-buffered LDS (128 KiB, 1 blk/CU).
//
// LEAN-WINDOW 2-barrier K-loop. Same two sync points as the R3 wide-window
// design, but peak live fragment count is halved (16 frags = 64 VGPR, peak
// ~220 total) so it fits the __launch_bounds__(512,2) 256-VGPR cap with NO
// spill -- R3/R4's wide window sat at ~250-260 and forced the allocator to
// the edge, the one structural difference from the R1/R2 kernels that ran.
// Per K-tile T (buf b = T&1):
//   1. read b0(4), a0(8), b1(4)      [16 frags live]
//   2. MFMA cluster 1 (a0 x b0, 32) -- compiler's counted lgkm waits overlap
//      these with the in-flight b1 reads; cross-wave overlap via 8 waves
//   3. read a1(8)                     [a0,b0 dead -> still <= 16 live]
//   4. lgkmcnt(0) + BAR              -> all waves done reading buf b
//   5. stage tile T+2 -> buf b       (8 global_load_lds per thread)
//   6. MFMA cluster 2 (a1 x b1, 32)  -- pure-register, overlaps stage flight
//   7. vmcnt(8) (T+2's loads stay in flight; forces T+1 landed) + BAR
// Hazard audit: barriers/guards block-uniform; per-wave vmcnt in-order
// (prologue 16 -> vmcnt(8) retires tile 0; each iter issues 8, retires 8);
// cross-wave tile-T+1 visibility = own-wave vmcnt(8) retire + barrier.
//
// Staging coalesced (8 rows x 128 B per instruction) with XOR involution
// (T2 / rule #21): source chunk = (l&7) ^ (row&7), LDS dest linear, ds_read
// chunk = (ks*4+quad) ^ (row&7). Measured conflict-free (BANK_CONFLICT = 0).
// T1: XCD-bijective block swizzle (m204 formula) for L2 locality.
// flags: 0 = fp32 out (at Cf + z*M*N for split-K), 1 = +add residual, 2 = bf16.
template<int ID>
__global__ __launch_bounds__(512, 2) void k_gemm256(
    const unsigned short* __restrict__ A, const unsigned short* __restrict__ B,
    int M, int N, int K, int Kslice,
    float* __restrict__ Cf, unsigned short* __restrict__ Cb,
    const float* __restrict__ add, int flags) {
    __shared__ __align__(16) unsigned short As[2][16384];   // [buf][row 256][k 64]
    __shared__ __align__(16) unsigned short Bs[2][16384];
    int tid = threadIdx.x;
    int wv = tid >> 6, lane = tid & 63, quad = lane >> 4, l15 = lane & 15;
    int wr = wv >> 2, wc = wv & 3;          // wave grid 2 (M) x 4 (N)

    // T1: XCD-bijective remap of the flattened block index.
    int gx = gridDim.x, gy = gridDim.y;
    int n_wg = gx * gy * gridDim.z;
    int lin = (blockIdx.z * gy + blockIdx.y) * gx + blockIdx.x;
    int q8 = n_wg >> 3, r8 = n_wg & 7;
    int xcd = lin & 7, idx8 = lin >> 3;
    int nl = (xcd < r8 ? xcd * (q8 + 1) : r8 * (q8 + 1) + (xcd - r8) * q8) + idx8;
    int bx = nl % gx; int rest = nl / gx;
    int by = rest % gy; int bz = rest / gy;

    int rowBase = by * 256;
    int colBase = bx * 256;
    int kb = bz * Kslice;
    int NT = Kslice >> 6;

    f32x4 acc[8][4] = {};

    int srow = lane >> 3;      // row within the 8-row group of one stage instr
    int schunk = lane & 7;     // linear LDS 16B-chunk within the row

    auto stage = [&](const unsigned short* Mat, int matBase,
                     unsigned short (*Ls)[16384], int t, int h, int b) {
#pragma unroll
        for (int j = 0; j < 2; j++) {
            int r0 = h * 128 + (j * 8 + wv) * 8;
            int row = r0 + srow;
            int kchunk = schunk ^ (row & 7);
            const unsigned short* g = Mat + (size_t)(matBase + row) * K
                                      + (kb + t * 64 + kchunk * 8);
            __builtin_amdgcn_global_load_lds(GPTR(g), LPTR(&Ls[b][r0 * 64]), 16, 0, 0);
        }
    };
    auto LDA = [&](int b_, int mt, int ks) -> s16x8 {
        int row = wr * 128 + mt * 16 + l15;
        return *(const s16x8*)&As[b_][row * 64 + ((((ks * 4 + quad)) ^ (row & 7)) << 3)];
    };
    auto LDB = [&](int b_, int nt, int ks) -> s16x8 {
        int row = wc * 64 + nt * 16 + l15;
        return *(const s16x8*)&Bs[b_][row * 64 + ((((ks * 4 + quad)) ^ (row & 7)) << 3)];
    };

    // Prologue: tile0 -> buf0 (8 loads/thread), tile1 -> buf1 (8 loads/thread).
    // vmcnt(8) forces tile0 landed, leaves tile1's 8 in flight.
    stage(B, colBase, Bs, 0, 0, 0); stage(B, colBase, Bs, 0, 1, 0);
    stage(A, rowBase, As, 0, 0, 0); stage(A, rowBase, As, 0, 1, 0);
    if (NT > 1) {
        stage(B, colBase, Bs, 1, 0, 1); stage(B, colBase, Bs, 1, 1, 1);
        stage(A, rowBase, As, 1, 0, 1); stage(A, rowBase, As, 1, 1, 1);
        asm volatile("s_waitcnt vmcnt(8)" ::: "memory");
    } else {
        asm volatile("s_waitcnt vmcnt(0)" ::: "memory");
    }
    BAR();

    for (int T = 0; T < NT; T++) {
        const int b = T & 1;
        s16x8 a0[8], b0[4], b1[4];
        // ---- read window 1: ks0 operands + b1 (16 frags, 64 VGPR) ----
#pragma unroll
        for (int nt = 0; nt < 4; nt++) b0[nt] = LDB(b, nt, 0);
#pragma unroll
        for (int mt = 0; mt < 8; mt++) a0[mt] = LDA(b, mt, 0);
#pragma unroll
        for (int nt = 0; nt < 4; nt++) b1[nt] = LDB(b, nt, 1);
        // ---- MFMA cluster 1 (ks0): overlaps the still-in-flight b1 reads
        __builtin_amdgcn_s_setprio(1);
#pragma unroll
        for (int mt = 0; mt < 8; mt++) {
            acc[mt][0] = __builtin_amdgcn_mfma_f32_16x16x32_bf16(a0[mt], b0[0], acc[mt][0], 0, 0, 0);
            acc[mt][1] = __builtin_amdgcn_mfma_f32_16x16x32_bf16(a0[mt], b0[1], acc[mt][1], 0, 0, 0);
            acc[mt][2] = __builtin_amdgcn_mfma_f32_16x16x32_bf16(a0[mt], b0[2], acc[mt][2], 0, 0, 0);
            acc[mt][3] = __builtin_amdgcn_mfma_f32_16x16x32_bf16(a0[mt], b0[3], acc[mt][3], 0, 0, 0);
        }
        __builtin_amdgcn_s_setprio(0);
        // ---- read window 2: a1 (a0/b0 now dead; live stays <= 16 frags)
        s16x8 a1[8];
#pragma unroll
        for (int mt = 0; mt < 8; mt++) a1[mt] = LDA(b, mt, 1);
        // ---- all waves done reading buf b -> safe to overwrite with T+2
        asm volatile("s_waitcnt lgkmcnt(0)" ::: "memory");
        BAR();
        if (T + 2 < NT) {
            stage(B, colBase, Bs, T + 2, 0, b); stage(B, colBase, Bs, T + 2, 1, b);
            stage(A, rowBase, As, T + 2, 0, b); stage(A, rowBase, As, T + 2, 1, b);
        }
        // ---- MFMA cluster 2 (ks1): pure-register, overlaps staging flight
        __builtin_amdgcn_s_setprio(1);
#pragma unroll
        for (int mt = 0; mt < 8; mt++) {
            acc[mt][0] = __builtin_amdgcn_mfma_f32_16x16x32_bf16(a1[mt], b1[0], acc[mt][0], 0, 0, 0);
            acc[mt][1] = __builtin_amdgcn_mfma_f32_16x16x32_bf16(a1[mt], b1[1], acc[mt][1], 0, 0, 0);
            acc[mt][2] = __builtin_amdgcn_mfma_f32_16x16x32_bf16(a1[mt], b1[2], acc[mt][2], 0, 0, 0);
            acc[mt][3] = __builtin_amdgcn_mfma_f32_16x16x32_bf16(a1[mt], b1[3], acc[mt][3], 0, 0, 0);
        }
        __builtin_amdgcn_s_setprio(0);
        if (T + 2 < NT) asm volatile("s_waitcnt vmcnt(8)" ::: "memory");
        else            asm volatile("s_waitcnt vmcnt(0)" ::: "memory");
        BAR();
    }

    float* Cfz = Cf ? Cf + (size_t)bz * M * N : nullptr;
#pragma unroll
    for (int mt = 0; mt < 8; mt++)
#pragma unroll
        for (int nt = 0; nt < 4; nt++)
#pragma unroll
            for (int r = 0; r < 4; r++) {
                int row = rowBase + wr * 128 + mt * 16 + quad * 4 + r;
                int col = colBase + wc * 64 + nt * 16 + l15;
                size_t idx = (size_t)row * N + col;
                float v = acc[mt][nt][r];
                if (flags == 1) v += add[idx];
                if (flags == 2) Cb[idx] = f2bf(v);
                else            Cfz[idx] = v;
            }
}

// ---------------- 5-way add (split-K x4 reduce + residual) ----------------
__global__ __launch_bounds__(256) void k_red5(const float* __restrict__ p,
                                              size_t pstride,
                                              const float* __restrict__ res,
                                              float* __restrict__ o, int n4) {
    int i = blockIdx.x * 256 + threadIdx.x;
    if (i < n4) {
        float4 r = ((const float4*)res)[i];
#pragma unroll
        for (int z = 0; z < 4; z++) {
            float4 v = ((const float4*)(p + z * pstride))[i];
            r.x += v.x; r.y += v.y; r.z += v.z; r.w += v.w;
        }
        ((float4*)o)[i] = r;
    }
}

// ---------------- per-head LayerNorm + RoPE for Q and K ----------------
// One wave per (s, head). Reads TWO split-K partials of the QKV GEMM and sums.
// Q: writes [16][SEQ][128] bf16, pre-scaled by log2e/sqrt(128).
// K: writes fragment-contiguous global layout [kvh][kt(32)][dgrp(16)][key(64)][8].
__global__ __launch_bounds__(256) void k_qknorm_rope(
    const float* __restrict__ qkv0, const float* __restrict__ qkv1,
    const float* __restrict__ qw, const float* __restrict__ qb,
    const float* __restrict__ kw, const float* __restrict__ kb,
    const float* __restrict__ fcos, const float* __restrict__ fsin,
    unsigned short* __restrict__ qout, unsigned short* __restrict__ kfrag) {
    int wv = threadIdx.x >> 6, lane = threadIdx.x & 63;
    int hl = blockIdx.y;              // 0..15 q-head, 16..23 k-head
    int s = blockIdx.x * 4 + wv;
    bool isq = hl < 16;
    size_t base = (size_t)s * QKV_N + hl * HD + 2 * lane;
    float2 u = *(const float2*)&qkv0[base];
    float2 w2v = *(const float2*)&qkv1[base];
    float2 xv; xv.x = u.x + w2v.x; xv.y = u.y + w2v.y;
    float sum = xv.x + xv.y, ssq = xv.x * xv.x + xv.y * xv.y;
    for (int off = 32; off >= 1; off >>= 1) {
        sum += __shfl_xor(sum, off);
        ssq += __shfl_xor(ssq, off);
    }
    float mu = sum * (1.0f / HD);
    float var = ssq * (1.0f / HD) - mu * mu;
    float rs = rsqrtf(var + 1e-5f);
    const float* w_ = isq ? qw : kw;
    const float* b_ = isq ? qb : kb;
    float n0 = (xv.x - mu) * rs * w_[2 * lane]     + b_[2 * lane];
    float n1 = (xv.y - mu) * rs * w_[2 * lane + 1] + b_[2 * lane + 1];
    float c = fcos[s * 64 + lane], sn = fsin[s * 64 + lane];
    float o0 = n0 * c - n1 * sn;
    float o1 = n0 * sn + n1 * c;
    if (isq) {
        const float sc = 0.12751744f;  // (1/sqrt(128)) * log2(e): softmax scale + exp2 fold
        o0 *= sc; o1 *= sc;
        unsigned val = (unsigned)f2bf(o0) | ((unsigned)f2bf(o1) << 16);
        *(unsigned*)&qout[((size_t)hl * SEQ + s) * HD + 2 * lane] = val;
    } else {
        int kvh = hl - 16;
        int kt = s >> 6, key = s & 63;
        int dg = lane >> 2, j = (2 * lane) & 7;
        unsigned val = (unsigned)f2bf(o0) | ((unsigned)f2bf(o1) << 16);
        size_t idx = (((size_t)(kvh * 32 + kt) * 16 + dg) * 64 + key) * 8 + j;
        *(unsigned*)&kfrag[idx] = val;
    }
}

// ---------------- V: fp32 (2 split-K partials) -> bf16 frag layout -----------
// out layout: [kvh][kt(32)][kgrp(8)][d(128)][8 keys]
__global__ __launch_bounds__(256) void k_vprep(const float* __restrict__ qkv0,
                                               const float* __restrict__ qkv1,
                                               unsigned short* __restrict__ vfrag) {
    __shared__ unsigned short lv[64][132];
    int kvh = blockIdx.y, kt = blockIdx.x, tid = threadIdx.x;
#pragma unroll
    for (int it = 0; it < 8; it++) {
        int li = it * 256 + tid;          // float4 index among 64*32
        int row = li >> 5;
        int c4 = (li & 31) * 4;
        size_t base = (size_t)(kt * 64 + row) * QKV_N + 3072 + kvh * HD + c4;
        float4 v = *(const float4*)&qkv0[base];
        float4 v1 = *(const float4*)&qkv1[base];
        v.x += v1.x; v.y += v1.y; v.z += v1.z; v.w += v1.w;
        lv[row][c4] = f2bf(v.x); lv[row][c4 + 1] = f2bf(v.y);
        lv[row][c4 + 2] = f2bf(v.z); lv[row][c4 + 3] = f2bf(v.w);
    }
    __syncthreads();
    size_t base = (size_t)(kvh * 32 + kt) * 8192;
#pragma unroll
    for (int it = 0; it < 16; it++) {
        int o2 = it * 256 + tid;          // uint index among 4096
        int e = o2 * 2;
        int r = e & 7, d = (e >> 3) & 127, kg = e >> 10;
        unsigned val = (unsigned)lv[kg * 8 + r][d] | ((unsigned)lv[kg * 8 + r + 1][d] << 16);
        *(unsigned*)&vfrag[base + e] = val;
    }
}

// ---------------- Flash attention, causal, GQA (2 q-heads per kv-head) ------
__global__ __launch_bounds__(256) void k_flash(
    const unsigned short* __restrict__ q,      // [16][SEQ][128], pre-scaled
    const unsigned short* __restrict__ kfrag,  // [8][32][16][64][8]
    const unsigned short* __restrict__ vfrag,  // [8][32][8][128][8]
    unsigned short* __restrict__ o) {          // [SEQ][2048]
    __shared__ __align__(16) unsigned short Ks[2][8192];
    __shared__ __align__(16) unsigned short Vs[2][8192];
    __shared__ __align__(16) unsigned short Ps[4][16 * 72];   // pad stride 72 (144B, 16B-aligned)
    int h = blockIdx.x & 15;
    int qt = 31 - (blockIdx.x >> 4);     // heavy (large qt) blocks launch first
    int kvh = h >> 1;
    int tid = threadIdx.x, wv = tid >> 6, lane = tid & 63, quad = lane >> 4, l15 = lane & 15;
    int qbase = qt * 64;

    s16x8 qf[4];
    {
        const unsigned short* qp = q + ((size_t)h * SEQ + qbase + wv * 16 + l15) * HD + quad * 8;
#pragma unroll
        for (int ks = 0; ks < 4; ks++) qf[ks] = *(const s16x8*)(qp + ks * 32);
    }
    f32x4 oacc[8] = {};
    float mst[4], lst[4];
#pragma unroll
    for (int r = 0; r < 4; r++) { mst[r] = -3e38f; lst[r] = 0.f; }

    auto issueKV = [&](int kt, int b) {
        size_t kb = (size_t)(kvh * 32 + kt) * 8192;
#pragma unroll
        for (int i = 0; i < 4; i++) {
            int s0 = i * 256 + wv * 64;
            __builtin_amdgcn_global_load_lds(GPTR(kfrag + kb + (size_t)(s0 + lane) * 8), LPTR(&Ks[b][s0 * 8]), 16, 0, 0);
            __builtin_amdgcn_global_load_lds(GPTR(vfrag + kb + (size_t)(s0 + lane) * 8), LPTR(&Vs[b][s0 * 8]), 16, 0, 0);
        }
    };

    issueKV(0, 0);
    for (int kt = 0; kt <= qt; kt++) {
        int b = kt & 1;
        __syncthreads();
        if (kt < qt) issueKV(kt + 1, b ^ 1);

        f32x4 sacc[4];
#pragma unroll
        for (int nt = 0; nt < 4; nt++) {
            f32x4 a = {};
#pragma unroll
            for (int ks = 0; ks < 4; ks++) {
                s16x8 kf = *(const s16x8*)&Ks[b][((ks * 4 + quad) * 64 + nt * 16 + l15) * 8];
                a = __builtin_amdgcn_mfma_f32_16x16x32_bf16(qf[ks], kf, a, 0, 0, 0);
            }
            sacc[nt] = a;
        }
        if (kt == qt) {   // diagonal tile: mask key > query
#pragma unroll
            for (int nt = 0; nt < 4; nt++) {
                int colg = kt * 64 + nt * 16 + l15;
#pragma unroll
                for (int r = 0; r < 4; r++) {
                    int rowg = qbase + wv * 16 + quad * 4 + r;
                    if (colg > rowg) sacc[nt][r] = -3e38f;
                }
            }
        }
        unsigned short* Pw = Ps[wv];
#pragma unroll
        for (int r = 0; r < 4; r++) {
            float mx = fmaxf(fmaxf(sacc[0][r], sacc[1][r]), fmaxf(sacc[2][r], sacc[3][r]));
#pragma unroll
            for (int off = 1; off < 16; off <<= 1) mx = fmaxf(mx, __shfl_xor(mx, off));
            float mnew = fmaxf(mst[r], mx);
            float alpha = exp2f(mst[r] - mnew);
            float psum = 0.f;
#pragma unroll
            for (int nt = 0; nt < 4; nt++) {
                float p = exp2f(sacc[nt][r] - mnew);
                psum += p;
                Pw[(quad * 4 + r) * 72 + nt * 16 + l15] = f2bf(p);
            }
#pragma unroll
            for (int off = 1; off < 16; off <<= 1) psum += __shfl_xor(psum, off);
            lst[r] = lst[r] * alpha + psum;
            mst[r] = mnew;
#pragma unroll
            for (int vt = 0; vt < 8; vt++) oacc[vt][r] *= alpha;
        }
        // PV: P through LDS into A-operand layout (m120-verified transform)
#pragma unroll
        for (int ks = 0; ks < 2; ks++) {
            s16x8 pf = *(const s16x8*)&Pw[l15 * 72 + ks * 32 + quad * 8];
#pragma unroll
            for (int vt = 0; vt < 8; vt++) {
                s16x8 vf = *(const s16x8*)&Vs[b][((ks * 4 + quad) * 128 + vt * 16 + l15) * 8];
                oacc[vt] = __builtin_amdgcn_mfma_f32_16x16x32_bf16(pf, vf, oacc[vt], 0, 0, 0);
            }
        }
    }
#pragma unroll
    for (int r = 0; r < 4; r++) {
        float inv = 1.0f / lst[r];
        int row = qbase + wv * 16 + quad * 4 + r;
#pragma unroll
        for (int vt = 0; vt < 8; vt++)
            o[(size_t)row * DIM + h * HD + vt * 16 + l15] = f2bf(oacc[vt][r] * inv);
    }
}

// ---------------- SwiGLU: y = silu(x1) * x3 ----------------
__global__ __launch_bounds__(256) void k_silu(const unsigned short* __restrict__ x13,
                                              unsigned short* __restrict__ y) {
    int gid = blockIdx.x * 256 + threadIdx.x;     // [0, 2048*1408)
    int s = gid / 1408;
    int j4 = (gid - s * 1408) * 4;
    const unsigned short* p1 = x13 + (size_t)s * FF_N + j4;
    const unsigned short* p3 = p1 + HIDDEN;
    ushort4 a = *(const ushort4*)p1;
    ushort4 b = *(const ushort4*)p3;
    ushort4 o;
    {
        float x1 = bf2f(a.x), x3 = bf2f(b.x);
        o.x = f2bf(x1 / (1.f + __expf(-x1)) * x3);
    }
    {
        float x1 = bf2f(a.y), x3 = bf2f(b.y);
        o.y = f2bf(x1 / (1.f + __expf(-x1)) * x3);
    }
    {
        float x1 = bf2f(a.z), x3 = bf2f(b.z);
        o.z = f2bf(x1 / (1.f + __expf(-x1)) * x3);
    }
    {
        float x1 = bf2f(a.w), x3 = bf2f(b.w);
        o.w = f2bf(x1 / (1.f + __expf(-x1)) * x3);
    }
    *(ushort4*)&y[(size_t)s * HIDDEN + j4] = o;
}

extern "C" void kernel_launch(void* const* d_in, const int* in_sizes, int n_in,
                              void* d_out, int out_size, void* d_ws, size_t ws_size,
                              hipStream_t stream) {
    const float* x    = (const float*)d_in[0];
    const float* fcos = (const float*)d_in[1];
    const float* fsin = (const float*)d_in[2];
    // d_in[3] = mask: causal, implemented directly
    const float* wqkv = (const float*)d_in[4];
    const float* wo   = (const float*)d_in[5];
    const float* qn_w = (const float*)d_in[6];
    const float* qn_b = (const float*)d_in[7];
    const float* kn_w = (const float*)d_in[8];
    const float* kn_b = (const float*)d_in[9];
    const float* anw  = (const float*)d_in[10];
    const float* fnw  = (const float*)d_in[11];
    const float* w13  = (const float*)d_in[12];
    const float* w2   = (const float*)d_in[13];
    float* out = (float*)d_out;
    char* ws = (char*)d_ws;

    size_t off = 0;
    auto alloc = [&](size_t bytes) { size_t o = off; off += (bytes + 255) & ~(size_t)255; return o; };
    unsigned short* wqkv_b = (unsigned short*)(ws + alloc((size_t)QKV_N * DIM * 2));
    unsigned short* wo_b   = (unsigned short*)(ws + alloc((size_t)DIM * DIM * 2));
    unsigned short* w13_b  = (unsigned short*)(ws + alloc((size_t)FF_N * DIM * 2));
    unsigned short* w2_b   = (unsigned short*)(ws + alloc((size_t)DIM * HIDDEN * 2));
    unsigned short* xn     = (unsigned short*)(ws + alloc((size_t)SEQ * DIM * 2));
    unsigned short* qb_    = (unsigned short*)(ws + alloc((size_t)NH * SEQ * HD * 2));
    unsigned short* kfr    = (unsigned short*)(ws + alloc((size_t)NKV * SEQ * HD * 2));
    unsigned short* vfr    = (unsigned short*)(ws + alloc((size_t)NKV * SEQ * HD * 2));
    unsigned short* ob     = (unsigned short*)(ws + alloc((size_t)SEQ * DIM * 2));
    float*          hbuf   = (float*)         (ws + alloc((size_t)SEQ * DIM * 4));
    unsigned short* gb     = (unsigned short*)(ws + alloc((size_t)SEQ * DIM * 2));
    unsigned short* x13b   = (unsigned short*)(ws + alloc((size_t)SEQ * FF_N * 2));
    unsigned short* yb     = (unsigned short*)(ws + alloc((size_t)SEQ * HIDDEN * 2));
    float*          pp     = (float*)         (ws + alloc((size_t)4 * SEQ * DIM * 4));
    const size_t pstride = (size_t)SEQ * DIM;
    // QKV split-K partials ALIASED onto pp (identical 64 MB size; disjoint
    // lifetimes: qkvp dies after k_vprep, pp first written by attn-proj GEMM).
    // Total ws footprint ~276 MB, below the R2-proven 308 MB.
    float* qkvp  = pp;
    const float* qkvp1 = qkvp + (size_t)SEQ * QKV_N;

    // weight conversions (per-call; ws is re-poisoned each launch)
    k_cvt<<<8192, 256, 0, stream>>>(wqkv, wqkv_b, QKV_N * DIM / 4);
    k_cvt<<<4096, 256, 0, stream>>>(wo, wo_b, DIM * DIM / 4);
    k_cvt<<<22528, 256, 0, stream>>>(w13, w13_b, FF_N * DIM / 4);
    k_cvt<<<11264, 256, 0, stream>>>(w2, w2_b, DIM * HIDDEN / 4);

    // h = rmsnorm(x, attn_norm_w) -> bf16
    k_rmsnorm<<<SEQ, 256, 0, stream>>>(x, anw, xn);
    // qkv = h @ wqkv^T, split-K x2 (16x8x2 = 256 blocks, NT=16, perfect packing)
    k_gemm256<0><<<dim3(QKV_N / 256, SEQ / 256, 2), 512, 0, stream>>>(
        xn, wqkv_b, SEQ, QKV_N, DIM, DIM / 2, qkvp, nullptr, nullptr, 0);
    // per-head LN + RoPE (sums the 2 partials), write q (scaled) and k (frag)
    k_qknorm_rope<<<dim3(SEQ / 4, NH + NKV), 256, 0, stream>>>(
        qkvp, qkvp1, qn_w, qn_b, kn_w, kn_b, fcos, fsin, qb_, kfr);
    // v -> bf16 frag layout (sums the 2 partials)
    k_vprep<<<dim3(SEQ / 64, NKV), 256, 0, stream>>>(qkvp, qkvp1, vfr);
    // flash attention
    k_flash<<<NH * (SEQ / 64), 256, 0, stream>>>(qb_, kfr, vfr, ob);
    // attn proj, split-K x4 (8x8x4 = 256 blocks, NT=8); hbuf = x + sum(partials)
    k_gemm256<1><<<dim3(DIM / 256, SEQ / 256, 4), 512, 0, stream>>>(
        ob, wo_b, SEQ, DIM, DIM, DIM / 4, pp, nullptr, nullptr, 0);
    k_red5<<<SEQ * DIM / 1024, 256, 0, stream>>>(pp, pstride, x, hbuf, SEQ * DIM / 4);
    // g = rmsnorm(h, ffn_norm_w) -> bf16
    k_rmsnorm<<<SEQ, 256, 0, stream>>>(hbuf, fnw, gb);
    // x13 = g @ w13^T (bf16 out); 44x8 = 352 blocks, NT=32
    k_gemm256<2><<<dim3(FF_N / 256, SEQ / 256), 512, 0, stream>>>(
        gb, w13_b, SEQ, FF_N, DIM, DIM, nullptr, x13b, nullptr, 2);
    // y = silu(x1) * x3
    k_silu<<<SEQ * (HIDDEN / 4) / 256, 256, 0, stream>>>(x13b, yb);
    // FFN down, split-K x4 (NT=22); out = hbuf + sum(partials)
    k_gemm256<3><<<dim3(DIM / 256, SEQ / 256, 4), 512, 0, stream>>>(
        yb, w2_b, SEQ, DIM, HIDDEN, HIDDEN / 4, pp, nullptr, nullptr, 0);
    k_red5<<<SEQ * DIM / 1024, 256, 0, stream>>>(pp, pstride, hbuf, out, SEQ * DIM / 4);
}

// Round 6
// 657.902 us; speedup vs baseline: 1.3522x; 1.0302x over previous
//
#include <hip/hip_runtime.h>
#include <math.h>

#define DIM 2048
#define SEQ 2048
#define NH 16
#define NKV 8
#define HD 128
#define HIDDEN 5632
#define QKV_N 4096   // (16 + 2*8) * 128
#define FF_N 11264   // 2*HIDDEN

typedef __attribute__((ext_vector_type(8))) short s16x8;   // 8 bf16 (4 VGPRs) MFMA A/B frag
typedef __attribute__((ext_vector_type(4))) float f32x4;   // MFMA C/D frag

#define GPTR(p) ((const __attribute__((address_space(1))) void*)(p))
#define LPTR(p) ((__attribute__((address_space(3))) void*)(p))

// Compiler memory fence + HW barrier. Raw s_barrier (NOT __syncthreads) so the
// compiler does not emit a vmcnt(0) drain -- counted vmcnt is the whole point.
#define CFENCE() __asm__ __volatile__("" ::: "memory")
#define BAR() do { CFENCE(); __builtin_amdgcn_s_barrier(); CFENCE(); } while (0)

__device__ __forceinline__ unsigned short f2bf(float f) {
    union { float f; unsigned u; } v; v.f = f;
    unsigned r = v.u + 0x7fff + ((v.u >> 16) & 1);   // RNE
    return (unsigned short)(r >> 16);
}
__device__ __forceinline__ float bf2f(unsigned short s) {
    union { unsigned u; float f; } v; v.u = ((unsigned)s) << 16;
    return v.f;
}

// ---------------- fp32 -> bf16 convert (weights) ----------------
__global__ __launch_bounds__(256) void k_cvt(const float* __restrict__ src,
                                             unsigned short* __restrict__ dst, int n4) {
    int i = blockIdx.x * 256 + threadIdx.x;
    if (i < n4) {
        float4 v = ((const float4*)src)[i];
        ushort4 o;
        o.x = f2bf(v.x); o.y = f2bf(v.y); o.z = f2bf(v.z); o.w = f2bf(v.w);
        ((ushort4*)dst)[i] = o;
    }
}

// ---------------- w13 convert + W1/W3 row interleave ----------------
// Original rows: 0..5631 = W1, 5632..11263 = W3. New row for original r:
// j = r mod 5632, g = j>>3, o = j&7 -> n' = 16g + o + (r<5632 ? 0 : 8).
// So each 16-row group holds {W1 rows 8g..8g+7, W3 rows 8g..8g+7} -- lets the
// FFN-up GEMM epilogue pair x1/x3 with a single __shfl_xor(8) and emit
// silu(x1)*x3 directly (kills the k_silu pass: 46+46+23 MB of HBM traffic).
__global__ __launch_bounds__(256) void k_cvt13(const float* __restrict__ src,
                                               unsigned short* __restrict__ dst) {
    int i = blockIdx.x * 256 + threadIdx.x;       // float4 index, 11264*512
    int r = i >> 9, c4 = i & 511;
    int j = (r < HIDDEN) ? r : r - HIDDEN;
    int np = ((j >> 3) << 4) + (j & 7) + ((r < HIDDEN) ? 0 : 8);
    float4 v = ((const float4*)src)[i];
    ushort4 o;
    o.x = f2bf(v.x); o.y = f2bf(v.y); o.z = f2bf(v.z); o.w = f2bf(v.w);
    ((ushort4*)dst)[np * 512 + c4] = o;
}

// ---------------- RMSNorm (fp32 in) -> bf16 out ----------------
__global__ __launch_bounds__(256) void k_rmsnorm(const float* __restrict__ x,
                                                 const float* __restrict__ w,
                                                 unsigned short* __restrict__ out) {
    int row = blockIdx.x;
    int tid = threadIdx.x, wv = tid >> 6, lane = tid & 63;
    const float* xr = x + (size_t)row * DIM;
    float4 a = ((const float4*)xr)[tid * 2];
    float4 b = ((const float4*)xr)[tid * 2 + 1];
    float ss = a.x*a.x + a.y*a.y + a.z*a.z + a.w*a.w
             + b.x*b.x + b.y*b.y + b.z*b.z + b.w*b.w;
    for (int off = 32; off >= 1; off >>= 1) ss += __shfl_xor(ss, off);
    __shared__ float red[4];
    if (lane == 0) red[wv] = ss;
    __syncthreads();
    float tot = red[0] + red[1] + red[2] + red[3];
    float rs = rsqrtf(tot * (1.0f / DIM) + 1e-5f);
    float4 wa = ((const float4*)w)[tid * 2];
    float4 wb = ((const float4*)w)[tid * 2 + 1];
    ushort4 o0, o1;
    o0.x = f2bf(a.x * rs * wa.x); o0.y = f2bf(a.y * rs * wa.y);
    o0.z = f2bf(a.z * rs * wa.z); o0.w = f2bf(a.w * rs * wa.w);
    o1.x = f2bf(b.x * rs * wb.x); o1.y = f2bf(b.y * rs * wb.y);
    o1.z = f2bf(b.z * rs * wb.z); o1.w = f2bf(b.w * rs * wb.w);
    ushort4* orow = (ushort4*)(out + (size_t)row * DIM);
    orow[tid * 2] = o0; orow[tid * 2 + 1] = o1;
}

// ---- fused: h = res + sum of 4 split-K partials; write h (fp32) and
//             rmsnorm(h, w) (bf16). One block per row. Replaces red5+rmsnorm.
__global__ __launch_bounds__(256) void k_rednorm(const float* __restrict__ p,
                                                 size_t pstride,
                                                 const float* __restrict__ res,
                                                 const float* __restrict__ w,
                                                 float* __restrict__ hout,
                                                 unsigned short* __restrict__ nout) {
    int row = blockIdx.x;
    int tid = threadIdx.x, wv = tid >> 6, lane = tid & 63;
    size_t base = (size_t)row * DIM;
    float4 a = ((const float4*)(res + base))[tid * 2];
    float4 b = ((const float4*)(res + base))[tid * 2 + 1];
#pragma unroll
    for (int z = 0; z < 4; z++) {
        float4 u = ((const float4*)(p + z * pstride + base))[tid * 2];
        float4 v = ((const float4*)(p + z * pstride + base))[tid * 2 + 1];
        a.x += u.x; a.y += u.y; a.z += u.z; a.w += u.w;
        b.x += v.x; b.y += v.y; b.z += v.z; b.w += v.w;
    }
    ((float4*)(hout + base))[tid * 2] = a;
    ((float4*)(hout + base))[tid * 2 + 1] = b;
    float ss = a.x*a.x + a.y*a.y + a.z*a.z + a.w*a.w
             + b.x*b.x + b.y*b.y + b.z*b.z + b.w*b.w;
    for (int off = 32; off >= 1; off >>= 1) ss += __shfl_xor(ss, off);
    __shared__ float red[4];
    if (lane == 0) red[wv] = ss;
    __syncthreads();
    float tot = red[0] + red[1] + red[2] + red[3];
    float rs = rsqrtf(tot * (1.0f / DIM) + 1e-5f);
    float4 wa = ((const float4*)w)[tid * 2];
    float4 wb = ((const float4*)w)[tid * 2 + 1];
    ushort4 o0, o1;
    o0.x = f2bf(a.x * rs * wa.x); o0.y = f2bf(a.y * rs * wa.y);
    o0.z = f2bf(a.z * rs * wa.z); o0.w = f2bf(a.w * rs * wa.w);
    o1.x = f2bf(b.x * rs * wb.x); o1.y = f2bf(b.y * rs * wb.y);
    o1.z = f2bf(b.z * rs * wb.z); o1.w = f2bf(b.w * rs * wb.w);
    ushort4* orow = (ushort4*)(nout + base);
    orow[tid * 2] = o0; orow[tid * 2 + 1] = o1;
}

// ---------------- bf16 GEMM: C[M,N] = A[M,K] @ B[N,K]^T (+fused epilogue) ----
// 256x256 tile, BK=64, 8 waves (2Mx4N), double-buffered LDS (128 KiB, 1 blk/CU).
// LEAN-WINDOW 2-barrier K-loop (see R5; VGPR 116, no spill, measured working).
//
// R6 change: XCD swizzle REMOVED. R5 counters: FETCH 127->188.6 MB on the
// identical FFN-up shape after adding the swizzle -- each XCD streaming the
// whole L3-fit B panel through its private 4 MB L2 (8x L2-miss on B) instead
// of the default dispatch where all XCDs share one A-row-panel and each B
// sub-panel is consumed by a single XCD. Swizzle only pays when HBM-bound
// with non-L3-fit operands (m160/m192); here everything is L3-fit.
//
// flags: 0 = fp32 out (at Cf + z*M*N for split-K), 2 = bf16 out,
//        3 = fused SwiGLU out (requires k_cvt13-interleaved B; writes
//            silu(x1)*x3 as bf16 [M][HIDDEN], cols paired via shfl_xor(8)).
template<int ID>
__global__ __launch_bounds__(512, 2) void k_gemm256(
    const unsigned short* __restrict__ A, const unsigned short* __restrict__ B,
    int M, int N, int K, int Kslice,
    float* __restrict__ Cf, unsigned short* __restrict__ Cb,
    const float* __restrict__ add, int flags) {
    __shared__ __align__(16) unsigned short As[2][16384];   // [buf][row 256][k 64]
    __shared__ __align__(16) unsigned short Bs[2][16384];
    int tid = threadIdx.x;
    int wv = tid >> 6, lane = tid & 63, quad = lane >> 4, l15 = lane & 15;
    int wr = wv >> 2, wc = wv & 3;          // wave grid 2 (M) x 4 (N)

    int rowBase = blockIdx.y * 256;
    int colBase = blockIdx.x * 256;
    int kb = blockIdx.z * Kslice;
    int NT = Kslice >> 6;

    f32x4 acc[8][4] = {};

    int srow = lane >> 3;      // row within the 8-row group of one stage instr
    int schunk = lane & 7;     // linear LDS 16B-chunk within the row

    auto stage = [&](const unsigned short* Mat, int matBase,
                     unsigned short (*Ls)[16384], int t, int h, int b) {
#pragma unroll
        for (int j = 0; j < 2; j++) {
            int r0 = h * 128 + (j * 8 + wv) * 8;
            int row = r0 + srow;
            int kchunk = schunk ^ (row & 7);
            const unsigned short* g = Mat + (size_t)(matBase + row) * K
                                      + (kb + t * 64 + kchunk * 8);
            __builtin_amdgcn_global_load_lds(GPTR(g), LPTR(&Ls[b][r0 * 64]), 16, 0, 0);
        }
    };
    auto LDA = [&](int b_, int mt, int ks) -> s16x8 {
        int row = wr * 128 + mt * 16 + l15;
        return *(const s16x8*)&As[b_][row * 64 + ((((ks * 4 + quad)) ^ (row & 7)) << 3)];
    };
    auto LDB = [&](int b_, int nt, int ks) -> s16x8 {
        int row = wc * 64 + nt * 16 + l15;
        return *(const s16x8*)&Bs[b_][row * 64 + ((((ks * 4 + quad)) ^ (row & 7)) << 3)];
    };

    // Prologue: tile0 -> buf0 (8 loads/thread), tile1 -> buf1 (8 loads/thread).
    // vmcnt(8) forces tile0 landed, leaves tile1's 8 in flight.
    stage(B, colBase, Bs, 0, 0, 0); stage(B, colBase, Bs, 0, 1, 0);
    stage(A, rowBase, As, 0, 0, 0); stage(A, rowBase, As, 0, 1, 0);
    if (NT > 1) {
        stage(B, colBase, Bs, 1, 0, 1); stage(B, colBase, Bs, 1, 1, 1);
        stage(A, rowBase, As, 1, 0, 1); stage(A, rowBase, As, 1, 1, 1);
        asm volatile("s_waitcnt vmcnt(8)" ::: "memory");
    } else {
        asm volatile("s_waitcnt vmcnt(0)" ::: "memory");
    }
    BAR();

    for (int T = 0; T < NT; T++) {
        const int b = T & 1;
        s16x8 a0[8], b0[4], b1[4];
        // ---- read window 1: ks0 operands + b1 (16 frags, 64 VGPR) ----
#pragma unroll
        for (int nt = 0; nt < 4; nt++) b0[nt] = LDB(b, nt, 0);
#pragma unroll
        for (int mt = 0; mt < 8; mt++) a0[mt] = LDA(b, mt, 0);
#pragma unroll
        for (int nt = 0; nt < 4; nt++) b1[nt] = LDB(b, nt, 1);
        // ---- MFMA cluster 1 (ks0): overlaps the still-in-flight b1 reads
        __builtin_amdgcn_s_setprio(1);
#pragma unroll
        for (int mt = 0; mt < 8; mt++) {
            acc[mt][0] = __builtin_amdgcn_mfma_f32_16x16x32_bf16(a0[mt], b0[0], acc[mt][0], 0, 0, 0);
            acc[mt][1] = __builtin_amdgcn_mfma_f32_16x16x32_bf16(a0[mt], b0[1], acc[mt][1], 0, 0, 0);
            acc[mt][2] = __builtin_amdgcn_mfma_f32_16x16x32_bf16(a0[mt], b0[2], acc[mt][2], 0, 0, 0);
            acc[mt][3] = __builtin_amdgcn_mfma_f32_16x16x32_bf16(a0[mt], b0[3], acc[mt][3], 0, 0, 0);
        }
        __builtin_amdgcn_s_setprio(0);
        // ---- read window 2: a1 (a0/b0 now dead; live stays <= 16 frags)
        s16x8 a1[8];
#pragma unroll
        for (int mt = 0; mt < 8; mt++) a1[mt] = LDA(b, mt, 1);
        // ---- all waves done reading buf b -> safe to overwrite with T+2
        asm volatile("s_waitcnt lgkmcnt(0)" ::: "memory");
        BAR();
        if (T + 2 < NT) {
            stage(B, colBase, Bs, T + 2, 0, b); stage(B, colBase, Bs, T + 2, 1, b);
            stage(A, rowBase, As, T + 2, 0, b); stage(A, rowBase, As, T + 2, 1, b);
        }
        // ---- MFMA cluster 2 (ks1): pure-register, overlaps staging flight
        __builtin_amdgcn_s_setprio(1);
#pragma unroll
        for (int mt = 0; mt < 8; mt++) {
            acc[mt][0] = __builtin_amdgcn_mfma_f32_16x16x32_bf16(a1[mt], b1[0], acc[mt][0], 0, 0, 0);
            acc[mt][1] = __builtin_amdgcn_mfma_f32_16x16x32_bf16(a1[mt], b1[1], acc[mt][1], 0, 0, 0);
            acc[mt][2] = __builtin_amdgcn_mfma_f32_16x16x32_bf16(a1[mt], b1[2], acc[mt][2], 0, 0, 0);
            acc[mt][3] = __builtin_amdgcn_mfma_f32_16x16x32_bf16(a1[mt], b1[3], acc[mt][3], 0, 0, 0);
        }
        __builtin_amdgcn_s_setprio(0);
        if (T + 2 < NT) asm volatile("s_waitcnt vmcnt(8)" ::: "memory");
        else            asm volatile("s_waitcnt vmcnt(0)" ::: "memory");
        BAR();
    }

    if (flags == 3) {
        // fused SwiGLU epilogue: 16-col group g holds x1_{8g..8g+7} (l15<8)
        // then x3_{8g..8g+7} (l15>=8); pair via shfl_xor(8), lanes <8 store.
#pragma unroll
        for (int mt = 0; mt < 8; mt++)
#pragma unroll
            for (int nt = 0; nt < 4; nt++) {
                int g = (colBase + wc * 64 + nt * 16) >> 4;
#pragma unroll
                for (int r = 0; r < 4; r++) {
                    int row = rowBase + wr * 128 + mt * 16 + quad * 4 + r;
                    float v = acc[mt][nt][r];
                    float prt = __shfl_xor(v, 8);
                    if (l15 < 8) {
                        float y = v / (1.f + __expf(-v)) * prt;
                        Cb[(size_t)row * HIDDEN + g * 8 + l15] = f2bf(y);
                    }
                }
            }
    } else {
        float* Cfz = Cf ? Cf + (size_t)blockIdx.z * M * N : nullptr;
#pragma unroll
        for (int mt = 0; mt < 8; mt++)
#pragma unroll
            for (int nt = 0; nt < 4; nt++)
#pragma unroll
                for (int r = 0; r < 4; r++) {
                    int row = rowBase + wr * 128 + mt * 16 + quad * 4 + r;
                    int col = colBase + wc * 64 + nt * 16 + l15;
                    size_t idx = (size_t)row * N + col;
                    float v = acc[mt][nt][r];
                    if (flags == 1) v += add[idx];
                    if (flags == 2) Cb[idx] = f2bf(v);
                    else            Cfz[idx] = v;
                }
    }
}

// ---------------- 5-way add (split-K x4 reduce + residual) ----------------
__global__ __launch_bounds__(256) void k_red5(const float* __restrict__ p,
                                              size_t pstride,
                                              const float* __restrict__ res,
                                              float* __restrict__ o, int n4) {
    int i = blockIdx.x * 256 + threadIdx.x;
    if (i < n4) {
        float4 r = ((const float4*)res)[i];
#pragma unroll
        for (int z = 0; z < 4; z++) {
            float4 v = ((const float4*)(p + z * pstride))[i];
            r.x += v.x; r.y += v.y; r.z += v.z; r.w += v.w;
        }
        ((float4*)o)[i] = r;
    }
}

// ---------------- per-head LayerNorm + RoPE for Q and K ----------------
// One wave per (s, head). Reads TWO split-K partials of the QKV GEMM and sums.
// Q: writes [16][SEQ][128] bf16, pre-scaled by log2e/sqrt(128).
// K: writes fragment-contiguous global layout [kvh][kt(32)][dgrp(16)][key(64)][8].
__global__ __launch_bounds__(256) void k_qknorm_rope(
    const float* __restrict__ qkv0, const float* __restrict__ qkv1,
    const float* __restrict__ qw, const float* __restrict__ qb,
    const float* __restrict__ kw, const float* __restrict__ kb,
    const float* __restrict__ fcos, const float* __restrict__ fsin,
    unsigned short* __restrict__ qout, unsigned short* __restrict__ kfrag) {
    int wv = threadIdx.x >> 6, lane = threadIdx.x & 63;
    int hl = blockIdx.y;              // 0..15 q-head, 16..23 k-head
    int s = blockIdx.x * 4 + wv;
    bool isq = hl < 16;
    size_t base = (size_t)s * QKV_N + hl * HD + 2 * lane;
    float2 u = *(const float2*)&qkv0[base];
    float2 w2v = *(const float2*)&qkv1[base];
    float2 xv; xv.x = u.x + w2v.x; xv.y = u.y + w2v.y;
    float sum = xv.x + xv.y, ssq = xv.x * xv.x + xv.y * xv.y;
    for (int off = 32; off >= 1; off >>= 1) {
        sum += __shfl_xor(sum, off);
        ssq += __shfl_xor(ssq, off);
    }
    float mu = sum * (1.0f / HD);
    float var = ssq * (1.0f / HD) - mu * mu;
    float rs = rsqrtf(var + 1e-5f);
    const float* w_ = isq ? qw : kw;
    const float* b_ = isq ? qb : kb;
    float n0 = (xv.x - mu) * rs * w_[2 * lane]     + b_[2 * lane];
    float n1 = (xv.y - mu) * rs * w_[2 * lane + 1] + b_[2 * lane + 1];
    float c = fcos[s * 64 + lane], sn = fsin[s * 64 + lane];
    float o0 = n0 * c - n1 * sn;
    float o1 = n0 * sn + n1 * c;
    if (isq) {
        const float sc = 0.12751744f;  // (1/sqrt(128)) * log2(e): softmax scale + exp2 fold
        o0 *= sc; o1 *= sc;
        unsigned val = (unsigned)f2bf(o0) | ((unsigned)f2bf(o1) << 16);
        *(unsigned*)&qout[((size_t)hl * SEQ + s) * HD + 2 * lane] = val;
    } else {
        int kvh = hl - 16;
        int kt = s >> 6, key = s & 63;
        int dg = lane >> 2, j = (2 * lane) & 7;
        unsigned val = (unsigned)f2bf(o0) | ((unsigned)f2bf(o1) << 16);
        size_t idx = (((size_t)(kvh * 32 + kt) * 16 + dg) * 64 + key) * 8 + j;
        *(unsigned*)&kfrag[idx] = val;
    }
}

// ---------------- V: fp32 (2 split-K partials) -> bf16 frag layout -----------
// out layout: [kvh][kt(32)][kgrp(8)][d(128)][8 keys]
__global__ __launch_bounds__(256) void k_vprep(const float* __restrict__ qkv0,
                                               const float* __restrict__ qkv1,
                                               unsigned short* __restrict__ vfrag) {
    __shared__ unsigned short lv[64][132];
    int kvh = blockIdx.y, kt = blockIdx.x, tid = threadIdx.x;
#pragma unroll
    for (int it = 0; it < 8; it++) {
        int li = it * 256 + tid;          // float4 index among 64*32
        int row = li >> 5;
        int c4 = (li & 31) * 4;
        size_t base = (size_t)(kt * 64 + row) * QKV_N + 3072 + kvh * HD + c4;
        float4 v = *(const float4*)&qkv0[base];
        float4 v1 = *(const float4*)&qkv1[base];
        v.x += v1.x; v.y += v1.y; v.z += v1.z; v.w += v1.w;
        lv[row][c4] = f2bf(v.x); lv[row][c4 + 1] = f2bf(v.y);
        lv[row][c4 + 2] = f2bf(v.z); lv[row][c4 + 3] = f2bf(v.w);
    }
    __syncthreads();
    size_t base = (size_t)(kvh * 32 + kt) * 8192;
#pragma unroll
    for (int it = 0; it < 16; it++) {
        int o2 = it * 256 + tid;          // uint index among 4096
        int e = o2 * 2;
        int r = e & 7, d = (e >> 3) & 127, kg = e >> 10;
        unsigned val = (unsigned)lv[kg * 8 + r][d] | ((unsigned)lv[kg * 8 + r + 1][d] << 16);
        *(unsigned*)&vfrag[base + e] = val;
    }
}

// ---------------- Flash attention, causal, GQA (2 q-heads per kv-head) ------
__global__ __launch_bounds__(256) void k_flash(
    const unsigned short* __restrict__ q,      // [16][SEQ][128], pre-scaled
    const unsigned short* __restrict__ kfrag,  // [8][32][16][64][8]
    const unsigned short* __restrict__ vfrag,  // [8][32][8][128][8]
    unsigned short* __restrict__ o) {          // [SEQ][2048]
    __shared__ __align__(16) unsigned short Ks[2][8192];
    __shared__ __align__(16) unsigned short Vs[2][8192];
    __shared__ __align__(16) unsigned short Ps[4][16 * 72];   // pad stride 72 (144B, 16B-aligned)
    int h = blockIdx.x & 15;
    int qt = 31 - (blockIdx.x >> 4);     // heavy (large qt) blocks launch first
    int kvh = h >> 1;
    int tid = threadIdx.x, wv = tid >> 6, lane = tid & 63, quad = lane >> 4, l15 = lane & 15;
    int qbase = qt * 64;

    s16x8 qf[4];
    {
        const unsigned short* qp = q + ((size_t)h * SEQ + qbase + wv * 16 + l15) * HD + quad * 8;
#pragma unroll
        for (int ks = 0; ks < 4; ks++) qf[ks] = *(const s16x8*)(qp + ks * 32);
    }
    f32x4 oacc[8] = {};
    float mst[4], lst[4];
#pragma unroll
    for (int r = 0; r < 4; r++) { mst[r] = -3e38f; lst[r] = 0.f; }

    auto issueKV = [&](int kt, int b) {
        size_t kb = (size_t)(kvh * 32 + kt) * 8192;
#pragma unroll
        for (int i = 0; i < 4; i++) {
            int s0 = i * 256 + wv * 64;
            __builtin_amdgcn_global_load_lds(GPTR(kfrag + kb + (size_t)(s0 + lane) * 8), LPTR(&Ks[b][s0 * 8]), 16, 0, 0);
            __builtin_amdgcn_global_load_lds(GPTR(vfrag + kb + (size_t)(s0 + lane) * 8), LPTR(&Vs[b][s0 * 8]), 16, 0, 0);
        }
    };

    issueKV(0, 0);
    for (int kt = 0; kt <= qt; kt++) {
        int b = kt & 1;
        __syncthreads();
        if (kt < qt) issueKV(kt + 1, b ^ 1);

        f32x4 sacc[4];
#pragma unroll
        for (int nt = 0; nt < 4; nt++) {
            f32x4 a = {};
#pragma unroll
            for (int ks = 0; ks < 4; ks++) {
                s16x8 kf = *(const s16x8*)&Ks[b][((ks * 4 + quad) * 64 + nt * 16 + l15) * 8];
                a = __builtin_amdgcn_mfma_f32_16x16x32_bf16(qf[ks], kf, a, 0, 0, 0);
            }
            sacc[nt] = a;
        }
        if (kt == qt) {   // diagonal tile: mask key > query
#pragma unroll
            for (int nt = 0; nt < 4; nt++) {
                int colg = kt * 64 + nt * 16 + l15;
#pragma unroll
                for (int r = 0; r < 4; r++) {
                    int rowg = qbase + wv * 16 + quad * 4 + r;
                    if (colg > rowg) sacc[nt][r] = -3e38f;
                }
            }
        }
        unsigned short* Pw = Ps[wv];
#pragma unroll
        for (int r = 0; r < 4; r++) {
            float mx = fmaxf(fmaxf(sacc[0][r], sacc[1][r]), fmaxf(sacc[2][r], sacc[3][r]));
#pragma unroll
            for (int off = 1; off < 16; off <<= 1) mx = fmaxf(mx, __shfl_xor(mx, off));
            float mnew = fmaxf(mst[r], mx);
            float alpha = exp2f(mst[r] - mnew);
            float psum = 0.f;
#pragma unroll
            for (int nt = 0; nt < 4; nt++) {
                float p = exp2f(sacc[nt][r] - mnew);
                psum += p;
                Pw[(quad * 4 + r) * 72 + nt * 16 + l15] = f2bf(p);
            }
#pragma unroll
            for (int off = 1; off < 16; off <<= 1) psum += __shfl_xor(psum, off);
            lst[r] = lst[r] * alpha + psum;
            mst[r] = mnew;
#pragma unroll
            for (int vt = 0; vt < 8; vt++) oacc[vt][r] *= alpha;
        }
        // PV: P through LDS into A-operand layout (m120-verified transform)
#pragma unroll
        for (int ks = 0; ks < 2; ks++) {
            s16x8 pf = *(const s16x8*)&Pw[l15 * 72 + ks * 32 + quad * 8];
#pragma unroll
            for (int vt = 0; vt < 8; vt++) {
                s16x8 vf = *(const s16x8*)&Vs[b][((ks * 4 + quad) * 128 + vt * 16 + l15) * 8];
                oacc[vt] = __builtin_amdgcn_mfma_f32_16x16x32_bf16(pf, vf, oacc[vt], 0, 0, 0);
            }
        }
    }
#pragma unroll
    for (int r = 0; r < 4; r++) {
        float inv = 1.0f / lst[r];
        int row = qbase + wv * 16 + quad * 4 + r;
#pragma unroll
        for (int vt = 0; vt < 8; vt++)
            o[(size_t)row * DIM + h * HD + vt * 16 + l15] = f2bf(oacc[vt][r] * inv);
    }
}

extern "C" void kernel_launch(void* const* d_in, const int* in_sizes, int n_in,
                              void* d_out, int out_size, void* d_ws, size_t ws_size,
                              hipStream_t stream) {
    const float* x    = (const float*)d_in[0];
    const float* fcos = (const float*)d_in[1];
    const float* fsin = (const float*)d_in[2];
    // d_in[3] = mask: causal, implemented directly
    const float* wqkv = (const float*)d_in[4];
    const float* wo   = (const float*)d_in[5];
    const float* qn_w = (const float*)d_in[6];
    const float* qn_b = (const float*)d_in[7];
    const float* kn_w = (const float*)d_in[8];
    const float* kn_b = (const float*)d_in[9];
    const float* anw  = (const float*)d_in[10];
    const float* fnw  = (const float*)d_in[11];
    const float* w13  = (const float*)d_in[12];
    const float* w2   = (const float*)d_in[13];
    float* out = (float*)d_out;
    char* ws = (char*)d_ws;

    size_t off = 0;
    auto alloc = [&](size_t bytes) { size_t o = off; off += (bytes + 255) & ~(size_t)255; return o; };
    unsigned short* wqkv_b = (unsigned short*)(ws + alloc((size_t)QKV_N * DIM * 2));
    unsigned short* wo_b   = (unsigned short*)(ws + alloc((size_t)DIM * DIM * 2));
    unsigned short* w13_b  = (unsigned short*)(ws + alloc((size_t)FF_N * DIM * 2));
    unsigned short* w2_b   = (unsigned short*)(ws + alloc((size_t)DIM * HIDDEN * 2));
    unsigned short* xn     = (unsigned short*)(ws + alloc((size_t)SEQ * DIM * 2));
    unsigned short* qb_    = (unsigned short*)(ws + alloc((size_t)NH * SEQ * HD * 2));
    unsigned short* kfr    = (unsigned short*)(ws + alloc((size_t)NKV * SEQ * HD * 2));
    unsigned short* vfr    = (unsigned short*)(ws + alloc((size_t)NKV * SEQ * HD * 2));
    unsigned short* ob     = (unsigned short*)(ws + alloc((size_t)SEQ * DIM * 2));
    float*          hbuf   = (float*)         (ws + alloc((size_t)SEQ * DIM * 4));
    unsigned short* gb     = (unsigned short*)(ws + alloc((size_t)SEQ * DIM * 2));
    unsigned short* yb     = (unsigned short*)(ws + alloc((size_t)SEQ * HIDDEN * 2));
    float*          pp     = (float*)         (ws + alloc((size_t)4 * SEQ * DIM * 4));
    const size_t pstride = (size_t)SEQ * DIM;
    // QKV split-K partials ALIASED onto pp (identical 64 MB size; disjoint
    // lifetimes: qkvp dies after k_vprep, pp first written by attn-proj GEMM).
    float* qkvp  = pp;
    const float* qkvp1 = qkvp + (size_t)SEQ * QKV_N;

    // weight conversions (per-call; ws is re-poisoned each launch)
    k_cvt<<<8192, 256, 0, stream>>>(wqkv, wqkv_b, QKV_N * DIM / 4);
    k_cvt<<<4096, 256, 0, stream>>>(wo, wo_b, DIM * DIM / 4);
    k_cvt13<<<22528, 256, 0, stream>>>(w13, w13_b);   // + W1/W3 interleave
    k_cvt<<<11264, 256, 0, stream>>>(w2, w2_b, DIM * HIDDEN / 4);

    // h = rmsnorm(x, attn_norm_w) -> bf16
    k_rmsnorm<<<SEQ, 256, 0, stream>>>(x, anw, xn);
    // qkv = h @ wqkv^T, split-K x2 (16x8x2 = 256 blocks, NT=16, perfect packing)
    k_gemm256<0><<<dim3(QKV_N / 256, SEQ / 256, 2), 512, 0, stream>>>(
        xn, wqkv_b, SEQ, QKV_N, DIM, DIM / 2, qkvp, nullptr, nullptr, 0);
    // per-head LN + RoPE (sums the 2 partials), write q (scaled) and k (frag)
    k_qknorm_rope<<<dim3(SEQ / 4, NH + NKV), 256, 0, stream>>>(
        qkvp, qkvp1, qn_w, qn_b, kn_w, kn_b, fcos, fsin, qb_, kfr);
    // v -> bf16 frag layout (sums the 2 partials)
    k_vprep<<<dim3(SEQ / 64, NKV), 256, 0, stream>>>(qkvp, qkvp1, vfr);
    // flash attention
    k_flash<<<NH * (SEQ / 64), 256, 0, stream>>>(qb_, kfr, vfr, ob);
    // attn proj, split-K x4 (8x8x4 = 256 blocks, NT=8) -> pp partials
    k_gemm256<1><<<dim3(DIM / 256, SEQ / 256, 4), 512, 0, stream>>>(
        ob, wo_b, SEQ, DIM, DIM, DIM / 4, pp, nullptr, nullptr, 0);
    // fused: h = x + sum(partials) -> hbuf; gb = rmsnorm(h, ffn_norm_w)
    k_rednorm<<<SEQ, 256, 0, stream>>>(pp, pstride, x, fnw, hbuf, gb);
    // FFN-up + fused SwiGLU epilogue: yb = silu(x1)*x3 directly
    k_gemm256<2><<<dim3(FF_N / 256, SEQ / 256), 512, 0, stream>>>(
        gb, w13_b, SEQ, FF_N, DIM, DIM, nullptr, yb, nullptr, 3);
    // FFN down, split-K x4 (NT=22); out = hbuf + sum(partials)
    k_gemm256<3><<<dim3(DIM / 256, SEQ / 256, 4), 512, 0, stream>>>(
        yb, w2_b, SEQ, DIM, HIDDEN, HIDDEN / 4, pp, nullptr, nullptr, 0);
    k_red5<<<SEQ * DIM / 1024, 256, 0, stream>>>(pp, pstride, hbuf, out, SEQ * DIM / 4);
}